// Round 7
// baseline (601.080 us; speedup 1.0000x reference)
//
#include <hip/hip_runtime.h>

using u16 = unsigned short;
using u32 = unsigned int;
typedef float f32x4 __attribute__((ext_vector_type(4)));
typedef float f32x2 __attribute__((ext_vector_type(2)));
typedef short s16x8 __attribute__((ext_vector_type(8)));
typedef u32   u32x2 __attribute__((ext_vector_type(2)));

// bf16 helpers via plain bit ops
__device__ __forceinline__ u16 f2bf(float f) {
  u32 u = __float_as_uint(f);
  u += 0x7fffu + ((u >> 16) & 1u);
  return (u16)(u >> 16);
}
__device__ __forceinline__ float bf2f(u16 h) {
  return __uint_as_float(((u32)h) << 16);
}

__global__ void ROEN_Final_33526514713351_kernel() {}

// Sentinel ladder: stage s writes 1000+s to d_out[s]; roen_final overwrites all.

// ---------- stage 0 ----------
__global__ void roen_zero(int* __restrict__ count, int N, float* __restrict__ dbg) {
  int i = blockIdx.x * 256 + threadIdx.x;
  if (i == 0) dbg[0] = 1000.0f;
  if (i < N) count[i] = 0;
}

// ---------- stage 1 ----------
__global__ void roen_hist(const int* __restrict__ ei, int E, int* __restrict__ count,
                          float* __restrict__ dbg) {
  int i = blockIdx.x * 256 + threadIdx.x;
  if (i == 0) dbg[1] = 1001.0f;
  if (i < E) atomicAdd(&count[ei[E + i]], 1);
}

// ---------- stage 2: exclusive scan ----------
__global__ __launch_bounds__(256) void roen_scan(const int* __restrict__ count, int N,
                                                 int* __restrict__ off, int* __restrict__ cursor,
                                                 float* __restrict__ dbg) {
  __shared__ int tsum[256];
  int tid = threadIdx.x;
  if (tid == 0) dbg[2] = 1002.0f;
  int chunk = (N + 255) / 256;
  int b = tid * chunk;
  int e = b + chunk; if (e > N) e = N; if (b > N) b = N;
  int s = 0;
  for (int i = b; i < e; ++i) s += count[i];
  tsum[tid] = s;
  __syncthreads();
  for (int d = 1; d < 256; d <<= 1) {
    int t = (tid >= d) ? tsum[tid - d] : 0;
    __syncthreads();
    tsum[tid] += t;
    __syncthreads();
  }
  int run = tsum[tid] - s;
  for (int i = b; i < e; ++i) {
    off[i] = run; cursor[i] = run;
    run += count[i];
  }
  if (tid == 255) off[N] = run;
}

// ---------- stage 3: inverse permutation + src in sorted order ----------
__global__ void roen_scatter(const int* __restrict__ ei, int E, int* __restrict__ cursor,
                             int* __restrict__ inv, int* __restrict__ srcS,
                             float* __restrict__ dbg) {
  int i = blockIdx.x * 256 + threadIdx.x;
  if (i == 0) dbg[3] = 1003.0f;
  if (i < E) {
    int s = ei[i];
    int d = ei[E + i];
    int p = atomicAdd(&cursor[d], 1);
    inv[i] = p;
    srcS[p] = s;
  }
}

// ---------- stage 4: weights f32 -> bf16 transposed: Wt[w][n*128+k] = W[k][n] ----------
__global__ void roen_prep_w(const float* __restrict__ W0, const float* __restrict__ W1,
                            const float* __restrict__ W2, const float* __restrict__ W3,
                            const float* __restrict__ W4, u16* __restrict__ Wt,
                            float* __restrict__ dbg) {
  int w = blockIdx.x;
  if (w == 0 && threadIdx.x == 0) dbg[4] = 1004.0f;
  const float* W = (w == 0) ? W0 : (w == 1) ? W1 : (w == 2) ? W2 : (w == 3) ? W3 : W4;
  for (int idx = threadIdx.x; idx < 16384; idx += 256) {
    int n = idx >> 7, k = idx & 127;
    Wt[w * 16384 + idx] = f2bf(W[k * 128 + n]);
  }
}

// ---------- stage 5: fused q/k/v GEMM. 64-row tile, batch-staged loads, bf16 out ----------
__global__ __launch_bounds__(256) void roen_gemm_qkv(const float* __restrict__ x,
                                                     const u16* __restrict__ Wt,
                                                     u16* __restrict__ qb, u16* __restrict__ kb,
                                                     u16* __restrict__ vb, int M,
                                                     float* __restrict__ dbg) {
  __shared__ u16 As[64 * 128];
  __shared__ u16 Bs[128 * 128];
  const int tid = threadIdx.x;
  if (blockIdx.x == 0 && tid == 0) dbg[5] = 1005.0f;
  const long brow = (long)blockIdx.x * 64;

  {
    f32x4 tmp[8];
#pragma unroll
    for (int j = 0; j < 8; ++j) {
      int idx = j * 256 + tid;
      int row = idx >> 5;
      int c4 = (idx & 31) * 4;
      long grow = brow + row;
      f32x4 a = {0.f, 0.f, 0.f, 0.f};
      if (grow < M) a = *(const f32x4*)(x + grow * 128 + c4);
      tmp[j] = a;
    }
#pragma unroll
    for (int j = 0; j < 8; ++j) {
      int idx = j * 256 + tid;
      int row = idx >> 5;
      int c4 = (idx & 31) * 4;
      u32 lo = ((u32)f2bf(tmp[j][1]) << 16) | (u32)f2bf(tmp[j][0]);
      u32 hi = ((u32)f2bf(tmp[j][3]) << 16) | (u32)f2bf(tmp[j][2]);
      int byte = (row * 256 + c4 * 2) ^ ((row & 7) << 4);
      u32x2 val; val[0] = lo; val[1] = hi;
      *(u32x2*)((char*)As + byte) = val;
    }
  }

  const int wave = tid >> 6, lane = tid & 63;
  const int wc = wave * 32;
  const int lr = lane & 15, lg = lane >> 4;

  for (int w = 0; w < 3; ++w) {
    if (w > 0) __syncthreads();
#pragma unroll
    for (int j = 0; j < 8; ++j) {
      int idx = j * 256 + tid;
      int n = idx >> 4;
      int k8 = (idx & 15) * 8;
      s16x8 val = *(const s16x8*)(Wt + w * 16384 + n * 128 + k8);
      int byte = (n * 256 + k8 * 2) ^ ((n & 7) << 4);
      *(s16x8*)((char*)Bs + byte) = val;
    }
    __syncthreads();

    f32x4 acc[4][2];
    for (int mt = 0; mt < 4; ++mt)
      for (int nt = 0; nt < 2; ++nt) acc[mt][nt] = {0.f, 0.f, 0.f, 0.f};

    for (int ks = 0; ks < 4; ++ks) {
      int kb2 = (ks * 32 + lg * 8) * 2;
      s16x8 af[4], bfr[2];
      for (int mt = 0; mt < 4; ++mt) {
        int row = mt * 16 + lr;
        int byte = (row * 256 + kb2) ^ ((row & 7) << 4);
        af[mt] = *(const s16x8*)((const char*)As + byte);
      }
      for (int nt = 0; nt < 2; ++nt) {
        int n = wc + nt * 16 + lr;
        int byte = (n * 256 + kb2) ^ ((n & 7) << 4);
        bfr[nt] = *(const s16x8*)((const char*)Bs + byte);
      }
      for (int mt = 0; mt < 4; ++mt)
        for (int nt = 0; nt < 2; ++nt)
          acc[mt][nt] = __builtin_amdgcn_mfma_f32_16x16x32_bf16(af[mt], bfr[nt], acc[mt][nt], 0, 0, 0);
    }

    u16* C = (w == 0) ? qb : (w == 1) ? kb : vb;
    for (int mt = 0; mt < 4; ++mt) {
      for (int nt = 0; nt < 2; ++nt) {
        int col = wc + nt * 16 + lr;
        for (int r = 0; r < 4; ++r) {
          long row = brow + mt * 16 + lg * 4 + r;
          if (row < M) C[row * 128 + col] = f2bf(acc[mt][nt][r]);
        }
      }
    }
  }
}

// ---------- stage 6: e-GEMM, streaming read, LDS-staged 256B scatter-write ----------
__global__ __launch_bounds__(256) void roen_gemm_e(const float* __restrict__ ea,
                                                   const u16* __restrict__ WtE,
                                                   const int* __restrict__ inv,
                                                   u16* __restrict__ eS, int E,
                                                   float* __restrict__ dbg) {
  __shared__ u16 As[128 * 128];
  __shared__ u16 Bs[128 * 128];
  __shared__ int invv[128];
  const int tid = threadIdx.x;
  if (blockIdx.x == 0 && tid == 0) dbg[6] = 1006.0f;
  const long brow = (long)blockIdx.x * 128;

  if (tid < 128) {
    long pos = brow + tid;
    invv[tid] = (pos < E) ? inv[pos] : -1;
  }

  // batch-staged sequential loads: 16 granules in flight, then convert+write
  {
    f32x4 tmp[16];
#pragma unroll
    for (int j = 0; j < 16; ++j) {
      int idx = j * 256 + tid;           // 4096 f32x4 granules
      int row = idx >> 5;                // 0..127
      int c4 = (idx & 31) * 4;
      long grow = brow + row;
      f32x4 a = {0.f, 0.f, 0.f, 0.f};
      if (grow < E) a = *(const f32x4*)(ea + grow * 128 + c4);
      tmp[j] = a;
    }
#pragma unroll
    for (int j = 0; j < 16; ++j) {
      int idx = j * 256 + tid;
      int row = idx >> 5;
      int c4 = (idx & 31) * 4;
      u32 lo = ((u32)f2bf(tmp[j][1]) << 16) | (u32)f2bf(tmp[j][0]);
      u32 hi = ((u32)f2bf(tmp[j][3]) << 16) | (u32)f2bf(tmp[j][2]);
      int byte = (row * 256 + c4 * 2) ^ ((row & 7) << 4);
      u32x2 val; val[0] = lo; val[1] = hi;
      *(u32x2*)((char*)As + byte) = val;
    }
  }
#pragma unroll
  for (int j = 0; j < 8; ++j) {
    int idx = j * 256 + tid;
    int n = idx >> 4;
    int k8 = (idx & 15) * 8;
    s16x8 val = *(const s16x8*)(WtE + n * 128 + k8);
    int byte = (n * 256 + k8 * 2) ^ ((n & 7) << 4);
    *(s16x8*)((char*)Bs + byte) = val;
  }
  __syncthreads();

  const int wave = tid >> 6, lane = tid & 63;
  const int wc = wave * 32;
  const int lr = lane & 15, lg = lane >> 4;
  f32x4 acc[8][2];
  for (int mt = 0; mt < 8; ++mt)
    for (int nt = 0; nt < 2; ++nt) acc[mt][nt] = {0.f, 0.f, 0.f, 0.f};

  for (int ks = 0; ks < 4; ++ks) {
    int kb2 = (ks * 32 + lg * 8) * 2;
    s16x8 af[8], bfr[2];
    for (int mt = 0; mt < 8; ++mt) {
      int row = mt * 16 + lr;
      int byte = (row * 256 + kb2) ^ ((row & 7) << 4);
      af[mt] = *(const s16x8*)((const char*)As + byte);
    }
    for (int nt = 0; nt < 2; ++nt) {
      int n = wc + nt * 16 + lr;
      int byte = (n * 256 + kb2) ^ ((n & 7) << 4);
      bfr[nt] = *(const s16x8*)((const char*)Bs + byte);
    }
    for (int mt = 0; mt < 8; ++mt)
      for (int nt = 0; nt < 2; ++nt)
        acc[mt][nt] = __builtin_amdgcn_mfma_f32_16x16x32_bf16(af[mt], bfr[nt], acc[mt][nt], 0, 0, 0);
  }

  // stage output tile in LDS (linear [row][col]), then write whole 256B rows
  __syncthreads();  // all As fragment reads complete
  for (int mt = 0; mt < 8; ++mt) {
    for (int nt = 0; nt < 2; ++nt) {
      int col = wc + nt * 16 + lr;
      for (int r = 0; r < 4; ++r) {
        int row = mt * 16 + lg * 4 + r;
        As[row * 128 + col] = f2bf(acc[mt][nt][r]);
      }
    }
  }
  __syncthreads();
  for (int rr = 0; rr < 32; ++rr) {
    int row = wave * 32 + rr;
    int op = invv[row];
    if (op >= 0) {
      u32 val = *(const u32*)((const char*)As + row * 256 + lane * 4);
      *(u32*)(eS + (long)op * 128 + lane * 2) = val;
    }
  }
}

// ---------- stage 11: GEMM (f32 A, f32 out) for out@Wout ----------
__global__ __launch_bounds__(256) void roen_gemm_f32(const float* __restrict__ A,
                                                     const u16* __restrict__ Wt,
                                                     float* __restrict__ Cf, int M,
                                                     float* __restrict__ dbg) {
  __shared__ u16 As[64 * 128];
  __shared__ u16 Bs[128 * 128];
  const int tid = threadIdx.x;
  if (blockIdx.x == 0 && tid == 0) dbg[11] = 1011.0f;
  const long brow = (long)blockIdx.x * 64;

  {
    f32x4 tmp[8];
#pragma unroll
    for (int j = 0; j < 8; ++j) {
      int idx = j * 256 + tid;
      int row = idx >> 5;
      int c4 = (idx & 31) * 4;
      long grow = brow + row;
      f32x4 a = {0.f, 0.f, 0.f, 0.f};
      if (grow < M) a = *(const f32x4*)(A + grow * 128 + c4);
      tmp[j] = a;
    }
#pragma unroll
    for (int j = 0; j < 8; ++j) {
      int idx = j * 256 + tid;
      int row = idx >> 5;
      int c4 = (idx & 31) * 4;
      u32 lo = ((u32)f2bf(tmp[j][1]) << 16) | (u32)f2bf(tmp[j][0]);
      u32 hi = ((u32)f2bf(tmp[j][3]) << 16) | (u32)f2bf(tmp[j][2]);
      int byte = (row * 256 + c4 * 2) ^ ((row & 7) << 4);
      u32x2 val; val[0] = lo; val[1] = hi;
      *(u32x2*)((char*)As + byte) = val;
    }
  }
#pragma unroll
  for (int j = 0; j < 8; ++j) {
    int idx = j * 256 + tid;
    int n = idx >> 4;
    int k8 = (idx & 15) * 8;
    s16x8 val = *(const s16x8*)(Wt + n * 128 + k8);
    int byte = (n * 256 + k8 * 2) ^ ((n & 7) << 4);
    *(s16x8*)((char*)Bs + byte) = val;
  }
  __syncthreads();

  const int wave = tid >> 6, lane = tid & 63;
  const int wc = wave * 32;
  const int lr = lane & 15, lg = lane >> 4;
  f32x4 acc[4][2];
  for (int mt = 0; mt < 4; ++mt)
    for (int nt = 0; nt < 2; ++nt) acc[mt][nt] = {0.f, 0.f, 0.f, 0.f};

  for (int ks = 0; ks < 4; ++ks) {
    int kb2 = (ks * 32 + lg * 8) * 2;
    s16x8 af[4], bfr[2];
    for (int mt = 0; mt < 4; ++mt) {
      int row = mt * 16 + lr;
      int byte = (row * 256 + kb2) ^ ((row & 7) << 4);
      af[mt] = *(const s16x8*)((const char*)As + byte);
    }
    for (int nt = 0; nt < 2; ++nt) {
      int n = wc + nt * 16 + lr;
      int byte = (n * 256 + kb2) ^ ((n & 7) << 4);
      bfr[nt] = *(const s16x8*)((const char*)Bs + byte);
    }
    for (int mt = 0; mt < 4; ++mt)
      for (int nt = 0; nt < 2; ++nt)
        acc[mt][nt] = __builtin_amdgcn_mfma_f32_16x16x32_bf16(af[mt], bfr[nt], acc[mt][nt], 0, 0, 0);
  }

  for (int mt = 0; mt < 4; ++mt) {
    for (int nt = 0; nt < 2; ++nt) {
      int col = wc + nt * 16 + lr;
      for (int r = 0; r < 4; ++r) {
        long row = brow + mt * 16 + lg * 4 + r;
        if (row < M) Cf[row * 128 + col] = acc[mt][nt][r];
      }
    }
  }
}

// ---------- stage 9: FUSED score + softmax + aggregation (wave per node) ----------
// Softmax without max-subtraction (shift-invariant; |s| bounded ~15, clamp 80).
__global__ __launch_bounds__(256) void roen_agg(const int* __restrict__ off,
                                                const int* __restrict__ srcS,
                                                const u16* __restrict__ qb,
                                                const u16* __restrict__ kb,
                                                const u16* __restrict__ eS,
                                                const u16* __restrict__ vb,
                                                float* __restrict__ outat, int N,
                                                float* __restrict__ dbg) {
  int wave = threadIdx.x >> 6;
  int lane = threadIdx.x & 63;
  int node = blockIdx.x * 4 + wave;
  if (node == 0 && lane == 0) dbg[9] = 1009.0f;
  if (node >= N) return;
  int beg = off[node], end = off[node + 1];

  int d0 = lane * 2;  // lane owns dims d0,d0+1; head = lane>>3
  u32 qv = *(const u32*)(qb + (long)node * 128 + d0);
  float q0 = bf2f((u16)(qv & 0xffffu)), q1 = bf2f((u16)(qv >> 16));

  float acc0 = 0.f, acc1 = 0.f, dsum = 0.f;
#pragma unroll 2
  for (int pos = beg; pos < end; ++pos) {
    int src = srcS[pos];
    u32 ev = *(const u32*)(eS + (long)pos * 128 + d0);
    u32 kv = *(const u32*)(kb + (long)src * 128 + d0);
    u32 vv = *(const u32*)(vb + (long)src * 128 + d0);
    float e0 = bf2f((u16)(ev & 0xffffu)), e1 = bf2f((u16)(ev >> 16));
    float k0 = bf2f((u16)(kv & 0xffffu)), k1 = bf2f((u16)(kv >> 16));
    float p = q0 * (k0 + e0) + q1 * (k1 + e1);
    // reduce across the 8 lanes of this head group (dims 16h..16h+15)
    p += __shfl_xor(p, 1);
    p += __shfl_xor(p, 2);
    p += __shfl_xor(p, 4);
    float w = __expf(fminf(p * 0.25f, 80.f));
    float v0 = bf2f((u16)(vv & 0xffffu)), v1 = bf2f((u16)(vv >> 16));
    acc0 += w * (v0 + e0);
    acc1 += w * (v1 + e1);
    dsum += w;
  }
  float inv = 1.f / (dsum + 1e-16f);
  outat[(long)node * 128 + d0] = acc0 * inv;
  outat[(long)node * 128 + d0 + 1] = acc1 * inv;
}

// ---------- stage 12: h = out2 + bout + x, block-partial column sums ----------
__global__ __launch_bounds__(256) void roen_h(const float* __restrict__ out2,
                                              const float* __restrict__ x,
                                              const float* __restrict__ bout,
                                              float* __restrict__ h,
                                              float* __restrict__ psum,
                                              float* __restrict__ psumsq, int N,
                                              float* __restrict__ dbg) {
  int d = threadIdx.x & 127;
  int half = threadIdx.x >> 7;
  if (blockIdx.x == 0 && threadIdx.x == 0) dbg[12] = 1012.0f;
  int rbase = blockIdx.x * 32 + half * 16;
  float b = bout[d];
  float s = 0.f, s2 = 0.f;
  for (int r = 0; r < 16; ++r) {
    int row = rbase + r;
    if (row < N) {
      long idx = (long)row * 128 + d;
      float val = out2[idx] + b + x[idx];
      h[idx] = val;
      s += val;
      s2 += val * val;
    }
  }
  __shared__ float sh[2][128], sh2[2][128];
  sh[half][d] = s;
  sh2[half][d] = s2;
  __syncthreads();
  if (half == 0) {
    psum[(long)blockIdx.x * 128 + d] = sh[0][d] + sh[1][d];
    psumsq[(long)blockIdx.x * 128 + d] = sh2[0][d] + sh2[1][d];
  }
}

// ---------- stage 13: GraphNorm coefficients ----------
__global__ void roen_stats(const float* __restrict__ psum, const float* __restrict__ psumsq,
                           const float* __restrict__ gnw, const float* __restrict__ gnb,
                           const float* __restrict__ gnms, float* __restrict__ Ac,
                           float* __restrict__ Bc, int nb, int N, float* __restrict__ dbg) {
  int d = threadIdx.x;
  if (d == 0) dbg[13] = 1013.0f;
  float s = 0.f, s2 = 0.f;
  for (int i = 0; i < nb; ++i) {
    s += psum[(long)i * 128 + d];
    s2 += psumsq[(long)i * 128 + d];
  }
  float mean = s / (float)N;
  float mm = mean * gnms[d];
  float var = s2 / (float)N - 2.f * mm * mean + mm * mm;
  float scale = gnw[d] * rsqrtf(var + 1e-5f);
  Ac[d] = scale;
  Bc[d] = gnb[d] - mm * scale;
}

// ---------- final: normalize + exact GELU -> f32 out ----------
__global__ __launch_bounds__(256) void roen_final(const float* __restrict__ h,
                                                  const float* __restrict__ Ac,
                                                  const float* __restrict__ Bc,
                                                  float* __restrict__ out, long total) {
  long i = (long)blockIdx.x * 256 + threadIdx.x;
  if (i >= total) return;
  int d = (int)(i & 127);
  float v = h[i] * Ac[d] + Bc[d];
  out[i] = 0.5f * v * (1.f + erff(v * 0.70710678f));
}

extern "C" void kernel_launch(void* const* d_in, const int* in_sizes, int n_in,
                              void* d_out, int out_size, void* d_ws, size_t ws_size,
                              hipStream_t stream) {
  const float* x   = (const float*)d_in[0];
  const int*   ei  = (const int*)d_in[1];
  const float* ea  = (const float*)d_in[2];
  const float* WQ  = (const float*)d_in[3];
  const float* WK  = (const float*)d_in[4];
  const float* WV  = (const float*)d_in[5];
  const float* WE  = (const float*)d_in[6];
  const float* Wo  = (const float*)d_in[7];
  const float* bo  = (const float*)d_in[8];
  const float* gnw = (const float*)d_in[9];
  const float* gnb = (const float*)d_in[10];
  const float* gnms= (const float*)d_in[11];
  float* out = (float*)d_out;
  float* dbg = (float*)d_out;

  const int N = in_sizes[0] / 128;   // 20000
  const int E = in_sizes[1] / 2;     // 640000
  const int nb = (N + 31) / 32;

  char* base = (char*)d_ws;
  size_t cur = 0;
  auto alloc = [&](size_t bytes) -> char* {
    char* r = base + cur;
    cur = (cur + bytes + 255) & ~(size_t)255;
    return r;
  };
  u16*   wt     = (u16*)alloc(5 * 16384 * sizeof(u16));
  u16*   qb     = (u16*)alloc((size_t)N * 128 * sizeof(u16));
  u16*   kb     = (u16*)alloc((size_t)N * 128 * sizeof(u16));
  u16*   vb     = (u16*)alloc((size_t)N * 128 * sizeof(u16));
  int*   count  = (int*)alloc((size_t)N * sizeof(int));
  int*   offar  = (int*)alloc((size_t)(N + 1) * sizeof(int));
  int*   cursor = (int*)alloc((size_t)N * sizeof(int));
  int*   invar  = (int*)alloc((size_t)E * sizeof(int));
  int*   srcS   = (int*)alloc((size_t)E * sizeof(int));
  float* outat  = (float*)alloc((size_t)N * 128 * sizeof(float));
  float* out2   = (float*)alloc((size_t)N * 128 * sizeof(float));
  float* psum   = (float*)alloc((size_t)nb * 128 * sizeof(float));
  float* psumsq = (float*)alloc((size_t)nb * 128 * sizeof(float));
  float* Ac     = (float*)alloc(128 * sizeof(float));
  float* Bc     = (float*)alloc(128 * sizeof(float));
  u16*   eS     = (u16*)alloc((size_t)E * 128 * sizeof(u16));  // 164 MB
  float* hbuf   = (float*)eS;  // alias: eS dead after roen_agg

  roen_zero<<<(N + 255) / 256, 256, 0, stream>>>(count, N, dbg);
  roen_hist<<<(E + 255) / 256, 256, 0, stream>>>(ei, E, count, dbg);
  roen_scan<<<1, 256, 0, stream>>>(count, N, offar, cursor, dbg);
  roen_scatter<<<(E + 255) / 256, 256, 0, stream>>>(ei, E, cursor, invar, srcS, dbg);
  roen_prep_w<<<5, 256, 0, stream>>>(WQ, WK, WV, WE, Wo, wt, dbg);

  roen_gemm_qkv<<<(N + 63) / 64, 256, 0, stream>>>(x, wt, qb, kb, vb, N, dbg);
  roen_gemm_e<<<(E + 127) / 128, 256, 0, stream>>>(ea, wt + 3 * 16384, invar, eS, E, dbg);

  roen_agg<<<(N + 3) / 4, 256, 0, stream>>>(offar, srcS, qb, kb, eS, vb, outat, N, dbg);

  roen_gemm_f32<<<(N + 63) / 64, 256, 0, stream>>>(outat, wt + 4 * 16384, out2, N, dbg);
  roen_h<<<nb, 256, 0, stream>>>(out2, x, bo, hbuf, psum, psumsq, N, dbg);
  roen_stats<<<1, 128, 0, stream>>>(psum, psumsq, gnw, gnb, gnms, Ac, Bc, nb, N, dbg);
  roen_final<<<(int)(((long)N * 128 + 255) / 256), 256, 0, stream>>>(hbuf, Ac, Bc, out, (long)N * 128);
}

// Round 8
// 550.553 us; speedup vs baseline: 1.0918x; 1.0918x over previous
//
#include <hip/hip_runtime.h>

using u16 = unsigned short;
using u32 = unsigned int;
typedef float f32x4 __attribute__((ext_vector_type(4)));
typedef float f32x2 __attribute__((ext_vector_type(2)));
typedef short s16x8 __attribute__((ext_vector_type(8)));
typedef u32   u32x2 __attribute__((ext_vector_type(2)));

// bf16 helpers via plain bit ops
__device__ __forceinline__ u16 f2bf(float f) {
  u32 u = __float_as_uint(f);
  u += 0x7fffu + ((u >> 16) & 1u);
  return (u16)(u >> 16);
}
__device__ __forceinline__ float bf2f(u16 h) {
  return __uint_as_float(((u32)h) << 16);
}

__global__ void ROEN_Final_33526514713351_kernel() {}

// Sentinel ladder: stage s writes 1000+s to d_out[s]; roen_final overwrites all.

// ---------- stage 0 ----------
__global__ void roen_zero(int* __restrict__ count, int N, float* __restrict__ dbg) {
  int i = blockIdx.x * 256 + threadIdx.x;
  if (i == 0) dbg[0] = 1000.0f;
  if (i < N) count[i] = 0;
}

// ---------- stage 1 ----------
__global__ void roen_hist(const int* __restrict__ ei, int E, int* __restrict__ count,
                          float* __restrict__ dbg) {
  int i = blockIdx.x * 256 + threadIdx.x;
  if (i == 0) dbg[1] = 1001.0f;
  if (i < E) atomicAdd(&count[ei[E + i]], 1);
}

// ---------- stage 2: exclusive scan ----------
__global__ __launch_bounds__(256) void roen_scan(const int* __restrict__ count, int N,
                                                 int* __restrict__ off, int* __restrict__ cursor,
                                                 float* __restrict__ dbg) {
  __shared__ int tsum[256];
  int tid = threadIdx.x;
  if (tid == 0) dbg[2] = 1002.0f;
  int chunk = (N + 255) / 256;
  int b = tid * chunk;
  int e = b + chunk; if (e > N) e = N; if (b > N) b = N;
  int s = 0;
  for (int i = b; i < e; ++i) s += count[i];
  tsum[tid] = s;
  __syncthreads();
  for (int d = 1; d < 256; d <<= 1) {
    int t = (tid >= d) ? tsum[tid - d] : 0;
    __syncthreads();
    tsum[tid] += t;
    __syncthreads();
  }
  int run = tsum[tid] - s;
  for (int i = b; i < e; ++i) {
    off[i] = run; cursor[i] = run;
    run += count[i];
  }
  if (tid == 255) off[N] = run;
}

// ---------- stage 3: inverse permutation + src/dst in sorted order ----------
__global__ void roen_scatter(const int* __restrict__ ei, int E, int* __restrict__ cursor,
                             int* __restrict__ inv, int* __restrict__ srcS,
                             int* __restrict__ dstS, float* __restrict__ dbg) {
  int i = blockIdx.x * 256 + threadIdx.x;
  if (i == 0) dbg[3] = 1003.0f;
  if (i < E) {
    int s = ei[i];
    int d = ei[E + i];
    int p = atomicAdd(&cursor[d], 1);
    inv[i] = p;
    srcS[p] = s;
    dstS[p] = d;
  }
}

// ---------- stage 4: weights f32 -> bf16 transposed: Wt[w][n*128+k] = W[k][n] ----------
__global__ void roen_prep_w(const float* __restrict__ W0, const float* __restrict__ W1,
                            const float* __restrict__ W2, const float* __restrict__ W3,
                            const float* __restrict__ W4, u16* __restrict__ Wt,
                            float* __restrict__ dbg) {
  int w = blockIdx.x;
  if (w == 0 && threadIdx.x == 0) dbg[4] = 1004.0f;
  const float* W = (w == 0) ? W0 : (w == 1) ? W1 : (w == 2) ? W2 : (w == 3) ? W3 : W4;
  for (int idx = threadIdx.x; idx < 16384; idx += 256) {
    int n = idx >> 7, k = idx & 127;
    Wt[w * 16384 + idx] = f2bf(W[k * 128 + n]);
  }
}

// ---------- stage 5: fused q/k/v GEMM. B fragments from global (L2-hot), no Bs LDS ----------
__global__ __launch_bounds__(256) void roen_gemm_qkv(const float* __restrict__ x,
                                                     const u16* __restrict__ Wt,
                                                     u16* __restrict__ qb, u16* __restrict__ kb,
                                                     u16* __restrict__ vb, int M,
                                                     float* __restrict__ dbg) {
  __shared__ u16 As[64 * 128];
  const int tid = threadIdx.x;
  if (blockIdx.x == 0 && tid == 0) dbg[5] = 1005.0f;
  const long brow = (long)blockIdx.x * 64;

  {
    f32x4 tmp[8];
#pragma unroll
    for (int j = 0; j < 8; ++j) {
      int idx = j * 256 + tid;
      int row = idx >> 5;
      int c4 = (idx & 31) * 4;
      long grow = brow + row;
      f32x4 a = {0.f, 0.f, 0.f, 0.f};
      if (grow < M) a = *(const f32x4*)(x + grow * 128 + c4);
      tmp[j] = a;
    }
#pragma unroll
    for (int j = 0; j < 8; ++j) {
      int idx = j * 256 + tid;
      int row = idx >> 5;
      int c4 = (idx & 31) * 4;
      u32 lo = ((u32)f2bf(tmp[j][1]) << 16) | (u32)f2bf(tmp[j][0]);
      u32 hi = ((u32)f2bf(tmp[j][3]) << 16) | (u32)f2bf(tmp[j][2]);
      int byte = (row * 256 + c4 * 2) ^ ((row & 7) << 4);
      u32x2 val; val[0] = lo; val[1] = hi;
      *(u32x2*)((char*)As + byte) = val;
    }
  }
  __syncthreads();

  const int wave = tid >> 6, lane = tid & 63;
  const int wc = wave * 32;
  const int lr = lane & 15, lg = lane >> 4;

  // A fragments are reused across the 3 weights: load once
  s16x8 af[4][4];  // [ks][mt]
#pragma unroll
  for (int ks = 0; ks < 4; ++ks) {
    int kb2 = (ks * 32 + lg * 8) * 2;
#pragma unroll
    for (int mt = 0; mt < 4; ++mt) {
      int row = mt * 16 + lr;
      int byte = (row * 256 + kb2) ^ ((row & 7) << 4);
      af[ks][mt] = *(const s16x8*)((const char*)As + byte);
    }
  }

  for (int w = 0; w < 3; ++w) {
    s16x8 bfr[4][2];  // [ks][nt] straight from global (L2-hot 32KB weight)
#pragma unroll
    for (int ks = 0; ks < 4; ++ks)
#pragma unroll
      for (int nt = 0; nt < 2; ++nt)
        bfr[ks][nt] = *(const s16x8*)(Wt + w * 16384 + (wc + nt * 16 + lr) * 128 + ks * 32 + lg * 8);

    f32x4 acc[4][2];
    for (int mt = 0; mt < 4; ++mt)
      for (int nt = 0; nt < 2; ++nt) acc[mt][nt] = {0.f, 0.f, 0.f, 0.f};

#pragma unroll
    for (int ks = 0; ks < 4; ++ks)
      for (int mt = 0; mt < 4; ++mt)
        for (int nt = 0; nt < 2; ++nt)
          acc[mt][nt] = __builtin_amdgcn_mfma_f32_16x16x32_bf16(af[ks][mt], bfr[ks][nt], acc[mt][nt], 0, 0, 0);

    u16* C = (w == 0) ? qb : (w == 1) ? kb : vb;
    for (int mt = 0; mt < 4; ++mt) {
      for (int nt = 0; nt < 2; ++nt) {
        int col = wc + nt * 16 + lr;
        for (int r = 0; r < 4; ++r) {
          long row = brow + mt * 16 + lg * 4 + r;
          if (row < M) C[row * 128 + col] = f2bf(acc[mt][nt][r]);
        }
      }
    }
  }
}

// ---------- stage 6: e-GEMM, streaming read, B from global, LDS-staged 256B scatter-write ----------
__global__ __launch_bounds__(256) void roen_gemm_e(const float* __restrict__ ea,
                                                   const u16* __restrict__ WtE,
                                                   const int* __restrict__ inv,
                                                   u16* __restrict__ eS, int E,
                                                   float* __restrict__ dbg) {
  __shared__ u16 As[128 * 128];
  __shared__ int invv[128];
  const int tid = threadIdx.x;
  if (blockIdx.x == 0 && tid == 0) dbg[6] = 1006.0f;
  const long brow = (long)blockIdx.x * 128;

  if (tid < 128) {
    long pos = brow + tid;
    invv[tid] = (pos < E) ? inv[pos] : -1;
  }

  // batch-staged sequential loads: 16 granules in flight, then convert+write
  {
    f32x4 tmp[16];
#pragma unroll
    for (int j = 0; j < 16; ++j) {
      int idx = j * 256 + tid;           // 4096 f32x4 granules
      int row = idx >> 5;                // 0..127
      int c4 = (idx & 31) * 4;
      long grow = brow + row;
      f32x4 a = {0.f, 0.f, 0.f, 0.f};
      if (grow < E) a = *(const f32x4*)(ea + grow * 128 + c4);
      tmp[j] = a;
    }
#pragma unroll
    for (int j = 0; j < 16; ++j) {
      int idx = j * 256 + tid;
      int row = idx >> 5;
      int c4 = (idx & 31) * 4;
      u32 lo = ((u32)f2bf(tmp[j][1]) << 16) | (u32)f2bf(tmp[j][0]);
      u32 hi = ((u32)f2bf(tmp[j][3]) << 16) | (u32)f2bf(tmp[j][2]);
      int byte = (row * 256 + c4 * 2) ^ ((row & 7) << 4);
      u32x2 val; val[0] = lo; val[1] = hi;
      *(u32x2*)((char*)As + byte) = val;
    }
  }

  const int wave = tid >> 6, lane = tid & 63;
  const int wc = wave * 32;
  const int lr = lane & 15, lg = lane >> 4;

  s16x8 bfr[4][2];
#pragma unroll
  for (int ks = 0; ks < 4; ++ks)
#pragma unroll
    for (int nt = 0; nt < 2; ++nt)
      bfr[ks][nt] = *(const s16x8*)(WtE + (wc + nt * 16 + lr) * 128 + ks * 32 + lg * 8);

  __syncthreads();

  f32x4 acc[8][2];
  for (int mt = 0; mt < 8; ++mt)
    for (int nt = 0; nt < 2; ++nt) acc[mt][nt] = {0.f, 0.f, 0.f, 0.f};

  for (int ks = 0; ks < 4; ++ks) {
    int kb2 = (ks * 32 + lg * 8) * 2;
    s16x8 af[8];
    for (int mt = 0; mt < 8; ++mt) {
      int row = mt * 16 + lr;
      int byte = (row * 256 + kb2) ^ ((row & 7) << 4);
      af[mt] = *(const s16x8*)((const char*)As + byte);
    }
    for (int mt = 0; mt < 8; ++mt)
      for (int nt = 0; nt < 2; ++nt)
        acc[mt][nt] = __builtin_amdgcn_mfma_f32_16x16x32_bf16(af[mt], bfr[ks][nt], acc[mt][nt], 0, 0, 0);
  }

  // stage output tile in LDS (linear [row][col]), then write whole 256B rows
  __syncthreads();  // all As fragment reads complete
  for (int mt = 0; mt < 8; ++mt) {
    for (int nt = 0; nt < 2; ++nt) {
      int col = wc + nt * 16 + lr;
      for (int r = 0; r < 4; ++r) {
        int row = mt * 16 + lg * 4 + r;
        As[row * 128 + col] = f2bf(acc[mt][nt][r]);
      }
    }
  }
  __syncthreads();
  for (int rr = 0; rr < 32; ++rr) {
    int row = wave * 32 + rr;
    int op = invv[row];
    if (op >= 0) {
      u32 val = *(const u32*)((const char*)As + row * 256 + lane * 4);
      *(u32*)(eS + (long)op * 128 + lane * 2) = val;
    }
  }
}

// ---------- stage 11: GEMM (f32 A, f32 out) for out@Wout ----------
__global__ __launch_bounds__(256) void roen_gemm_f32(const float* __restrict__ A,
                                                     const u16* __restrict__ Wt,
                                                     float* __restrict__ Cf, int M,
                                                     float* __restrict__ dbg) {
  __shared__ u16 As[64 * 128];
  const int tid = threadIdx.x;
  if (blockIdx.x == 0 && tid == 0) dbg[11] = 1011.0f;
  const long brow = (long)blockIdx.x * 64;

  {
    f32x4 tmp[8];
#pragma unroll
    for (int j = 0; j < 8; ++j) {
      int idx = j * 256 + tid;
      int row = idx >> 5;
      int c4 = (idx & 31) * 4;
      long grow = brow + row;
      f32x4 a = {0.f, 0.f, 0.f, 0.f};
      if (grow < M) a = *(const f32x4*)(A + grow * 128 + c4);
      tmp[j] = a;
    }
#pragma unroll
    for (int j = 0; j < 8; ++j) {
      int idx = j * 256 + tid;
      int row = idx >> 5;
      int c4 = (idx & 31) * 4;
      u32 lo = ((u32)f2bf(tmp[j][1]) << 16) | (u32)f2bf(tmp[j][0]);
      u32 hi = ((u32)f2bf(tmp[j][3]) << 16) | (u32)f2bf(tmp[j][2]);
      int byte = (row * 256 + c4 * 2) ^ ((row & 7) << 4);
      u32x2 val; val[0] = lo; val[1] = hi;
      *(u32x2*)((char*)As + byte) = val;
    }
  }

  const int wave = tid >> 6, lane = tid & 63;
  const int wc = wave * 32;
  const int lr = lane & 15, lg = lane >> 4;

  s16x8 bfr[4][2];
#pragma unroll
  for (int ks = 0; ks < 4; ++ks)
#pragma unroll
    for (int nt = 0; nt < 2; ++nt)
      bfr[ks][nt] = *(const s16x8*)(Wt + (wc + nt * 16 + lr) * 128 + ks * 32 + lg * 8);

  __syncthreads();

  f32x4 acc[4][2];
  for (int mt = 0; mt < 4; ++mt)
    for (int nt = 0; nt < 2; ++nt) acc[mt][nt] = {0.f, 0.f, 0.f, 0.f};

  for (int ks = 0; ks < 4; ++ks) {
    int kb2 = (ks * 32 + lg * 8) * 2;
    s16x8 af[4];
    for (int mt = 0; mt < 4; ++mt) {
      int row = mt * 16 + lr;
      int byte = (row * 256 + kb2) ^ ((row & 7) << 4);
      af[mt] = *(const s16x8*)((const char*)As + byte);
    }
    for (int mt = 0; mt < 4; ++mt)
      for (int nt = 0; nt < 2; ++nt)
        acc[mt][nt] = __builtin_amdgcn_mfma_f32_16x16x32_bf16(af[mt], bfr[ks][nt], acc[mt][nt], 0, 0, 0);
  }

  for (int mt = 0; mt < 4; ++mt) {
    for (int nt = 0; nt < 2; ++nt) {
      int col = wc + nt * 16 + lr;
      for (int r = 0; r < 4; ++r) {
        long row = brow + mt * 16 + lg * 4 + r;
        if (row < M) Cf[row * 128 + col] = acc[mt][nt][r];
      }
    }
  }
}

// ---------- stage 9: score -> softmax weight w = exp(min(s/4,80)) (E x 8 parallel) ----------
__global__ __launch_bounds__(256) void roen_score(const int* __restrict__ srcS,
                                                  const int* __restrict__ dstS,
                                                  const u16* __restrict__ qb,
                                                  const u16* __restrict__ kb,
                                                  const u16* __restrict__ eS,
                                                  float* __restrict__ wS, int E,
                                                  float* __restrict__ dbg) {
  long gid = (long)blockIdx.x * 256 + threadIdx.x;
  if (gid == 0) dbg[9] = 1009.0f;
  long pos = gid >> 3;
  int h = (int)(gid & 7);
  if (pos >= E) return;
  int dst = dstS[pos], src = srcS[pos];
  const s16x8* qp = (const s16x8*)(qb + (long)dst * 128 + h * 16);
  const s16x8* kp = (const s16x8*)(kb + (long)src * 128 + h * 16);
  const s16x8* ep = (const s16x8*)(eS + pos * 128 + h * 16);
  float acc = 0.f;
#pragma unroll
  for (int half = 0; half < 2; ++half) {
    s16x8 qv = qp[half], kv = kp[half], ev = ep[half];
#pragma unroll
    for (int j = 0; j < 8; ++j)
      acc += bf2f((u16)qv[j]) * (bf2f((u16)kv[j]) + bf2f((u16)ev[j]));
  }
  wS[pos * 8 + h] = __expf(fminf(acc * 0.25f, 80.f));
}

// ---------- stage 10: per-node weighted aggregation (no max pass, no exp) ----------
__global__ __launch_bounds__(256) void roen_node_agg(const int* __restrict__ off,
                                                     const int* __restrict__ srcS,
                                                     const u16* __restrict__ eS,
                                                     const u16* __restrict__ vb,
                                                     const float* __restrict__ wS,
                                                     float* __restrict__ outat, int N,
                                                     float* __restrict__ dbg) {
  int wave = threadIdx.x >> 6;
  int lane = threadIdx.x & 63;
  int node = blockIdx.x * 4 + wave;
  if (node == 0 && lane == 0) dbg[10] = 1010.0f;
  if (node >= N) return;
  int beg = off[node], end = off[node + 1];

  int d0 = lane * 2;   // lane owns dims d0,d0+1
  int hh = lane >> 3;  // head of those dims
  float acc0 = 0.f, acc1 = 0.f, dsum = 0.f;
#pragma unroll 2
  for (int pos = beg; pos < end; ++pos) {
    float w = wS[(long)pos * 8 + hh];
    u32 ev = *(const u32*)(eS + (long)pos * 128 + d0);
    int src = srcS[pos];
    u32 vv = *(const u32*)(vb + (long)src * 128 + d0);
    acc0 += w * (bf2f((u16)(vv & 0xffffu)) + bf2f((u16)(ev & 0xffffu)));
    acc1 += w * (bf2f((u16)(vv >> 16)) + bf2f((u16)(ev >> 16)));
    dsum += w;
  }
  float inv = 1.f / (dsum + 1e-16f);
  outat[(long)node * 128 + d0] = acc0 * inv;
  outat[(long)node * 128 + d0 + 1] = acc1 * inv;
}

// ---------- stage 12: h = out2 + bout + x, block-partial column sums ----------
__global__ __launch_bounds__(256) void roen_h(const float* __restrict__ out2,
                                              const float* __restrict__ x,
                                              const float* __restrict__ bout,
                                              float* __restrict__ h,
                                              float* __restrict__ psum,
                                              float* __restrict__ psumsq, int N,
                                              float* __restrict__ dbg) {
  int d = threadIdx.x & 127;
  int half = threadIdx.x >> 7;
  if (blockIdx.x == 0 && threadIdx.x == 0) dbg[12] = 1012.0f;
  int rbase = blockIdx.x * 32 + half * 16;
  float b = bout[d];
  float s = 0.f, s2 = 0.f;
  for (int r = 0; r < 16; ++r) {
    int row = rbase + r;
    if (row < N) {
      long idx = (long)row * 128 + d;
      float val = out2[idx] + b + x[idx];
      h[idx] = val;
      s += val;
      s2 += val * val;
    }
  }
  __shared__ float sh[2][128], sh2[2][128];
  sh[half][d] = s;
  sh2[half][d] = s2;
  __syncthreads();
  if (half == 0) {
    psum[(long)blockIdx.x * 128 + d] = sh[0][d] + sh[1][d];
    psumsq[(long)blockIdx.x * 128 + d] = sh2[0][d] + sh2[1][d];
  }
}

// ---------- stage 13: GraphNorm coefficients ----------
__global__ void roen_stats(const float* __restrict__ psum, const float* __restrict__ psumsq,
                           const float* __restrict__ gnw, const float* __restrict__ gnb,
                           const float* __restrict__ gnms, float* __restrict__ Ac,
                           float* __restrict__ Bc, int nb, int N, float* __restrict__ dbg) {
  int d = threadIdx.x;
  if (d == 0) dbg[13] = 1013.0f;
  float s = 0.f, s2 = 0.f;
  for (int i = 0; i < nb; ++i) {
    s += psum[(long)i * 128 + d];
    s2 += psumsq[(long)i * 128 + d];
  }
  float mean = s / (float)N;
  float mm = mean * gnms[d];
  float var = s2 / (float)N - 2.f * mm * mean + mm * mm;
  float scale = gnw[d] * rsqrtf(var + 1e-5f);
  Ac[d] = scale;
  Bc[d] = gnb[d] - mm * scale;
}

// ---------- final: normalize + exact GELU -> f32 out ----------
__global__ __launch_bounds__(256) void roen_final(const float* __restrict__ h,
                                                  const float* __restrict__ Ac,
                                                  const float* __restrict__ Bc,
                                                  float* __restrict__ out, long total) {
  long i = (long)blockIdx.x * 256 + threadIdx.x;
  if (i >= total) return;
  int d = (int)(i & 127);
  float v = h[i] * Ac[d] + Bc[d];
  out[i] = 0.5f * v * (1.f + erff(v * 0.70710678f));
}

extern "C" void kernel_launch(void* const* d_in, const int* in_sizes, int n_in,
                              void* d_out, int out_size, void* d_ws, size_t ws_size,
                              hipStream_t stream) {
  const float* x   = (const float*)d_in[0];
  const int*   ei  = (const int*)d_in[1];
  const float* ea  = (const float*)d_in[2];
  const float* WQ  = (const float*)d_in[3];
  const float* WK  = (const float*)d_in[4];
  const float* WV  = (const float*)d_in[5];
  const float* WE  = (const float*)d_in[6];
  const float* Wo  = (const float*)d_in[7];
  const float* bo  = (const float*)d_in[8];
  const float* gnw = (const float*)d_in[9];
  const float* gnb = (const float*)d_in[10];
  const float* gnms= (const float*)d_in[11];
  float* out = (float*)d_out;
  float* dbg = (float*)d_out;

  const int N = in_sizes[0] / 128;   // 20000
  const int E = in_sizes[1] / 2;     // 640000
  const int nb = (N + 31) / 32;

  char* base = (char*)d_ws;
  size_t cur = 0;
  auto alloc = [&](size_t bytes) -> char* {
    char* r = base + cur;
    cur = (cur + bytes + 255) & ~(size_t)255;
    return r;
  };
  u16*   wt     = (u16*)alloc(5 * 16384 * sizeof(u16));
  u16*   qb     = (u16*)alloc((size_t)N * 128 * sizeof(u16));
  u16*   kb     = (u16*)alloc((size_t)N * 128 * sizeof(u16));
  u16*   vb     = (u16*)alloc((size_t)N * 128 * sizeof(u16));
  float* wS     = (float*)alloc((size_t)E * 8 * sizeof(float));
  int*   count  = (int*)alloc((size_t)N * sizeof(int));
  int*   offar  = (int*)alloc((size_t)(N + 1) * sizeof(int));
  int*   cursor = (int*)alloc((size_t)N * sizeof(int));
  int*   invar  = (int*)alloc((size_t)E * sizeof(int));
  int*   srcS   = (int*)alloc((size_t)E * sizeof(int));
  int*   dstS   = (int*)alloc((size_t)E * sizeof(int));
  float* outat  = (float*)alloc((size_t)N * 128 * sizeof(float));
  float* out2   = (float*)alloc((size_t)N * 128 * sizeof(float));
  float* psum   = (float*)alloc((size_t)nb * 128 * sizeof(float));
  float* psumsq = (float*)alloc((size_t)nb * 128 * sizeof(float));
  float* Ac     = (float*)alloc(128 * sizeof(float));
  float* Bc     = (float*)alloc(128 * sizeof(float));
  u16*   eS     = (u16*)alloc((size_t)E * 128 * sizeof(u16));  // 164 MB
  float* hbuf   = (float*)eS;  // alias: eS dead after node_agg

  roen_zero<<<(N + 255) / 256, 256, 0, stream>>>(count, N, dbg);
  roen_hist<<<(E + 255) / 256, 256, 0, stream>>>(ei, E, count, dbg);
  roen_scan<<<1, 256, 0, stream>>>(count, N, offar, cursor, dbg);
  roen_scatter<<<(E + 255) / 256, 256, 0, stream>>>(ei, E, cursor, invar, srcS, dstS, dbg);
  roen_prep_w<<<5, 256, 0, stream>>>(WQ, WK, WV, WE, Wo, wt, dbg);

  roen_gemm_qkv<<<(N + 63) / 64, 256, 0, stream>>>(x, wt, qb, kb, vb, N, dbg);
  roen_gemm_e<<<(E + 127) / 128, 256, 0, stream>>>(ea, wt + 3 * 16384, invar, eS, E, dbg);

  roen_score<<<(int)(((long)E * 8 + 255) / 256), 256, 0, stream>>>(srcS, dstS, qb, kb, eS, wS, E, dbg);
  roen_node_agg<<<(N + 3) / 4, 256, 0, stream>>>(offar, srcS, eS, vb, wS, outat, N, dbg);

  roen_gemm_f32<<<(N + 63) / 64, 256, 0, stream>>>(outat, wt + 4 * 16384, out2, N, dbg);
  roen_h<<<nb, 256, 0, stream>>>(out2, x, bo, hbuf, psum, psumsq, N, dbg);
  roen_stats<<<1, 128, 0, stream>>>(psum, psumsq, gnw, gnb, gnms, Ac, Bc, nb, N, dbg);
  roen_final<<<(int)(((long)N * 128 + 255) / 256), 256, 0, stream>>>(hbuf, Ac, Bc, out, (long)N * 128);
}

// Round 9
// 502.658 us; speedup vs baseline: 1.1958x; 1.0953x over previous
//
#include <hip/hip_runtime.h>

using u16 = unsigned short;
using u32 = unsigned int;
typedef float f32x4 __attribute__((ext_vector_type(4)));
typedef short s16x8 __attribute__((ext_vector_type(8)));
typedef u32   u32x2 __attribute__((ext_vector_type(2)));

__device__ __forceinline__ u16 f2bf(float f) {
  u32 u = __float_as_uint(f);
  u += 0x7fffu + ((u >> 16) & 1u);
  return (u16)(u >> 16);
}
__device__ __forceinline__ float bf2f(u16 h) {
  return __uint_as_float(((u32)h) << 16);
}

__global__ void ROEN_Final_33526514713351_kernel() {}

// Sentinel ladder: stage s writes 1000+s to d_out[s]; roen_final overwrites all.

// ---------- stage 0 ----------
__global__ void roen_zero(int* __restrict__ count, int N, float* __restrict__ dbg) {
  int i = blockIdx.x * 256 + threadIdx.x;
  if (i == 0) dbg[0] = 1000.0f;
  if (i < N) count[i] = 0;
}

// ---------- stage 1 ----------
__global__ void roen_hist(const int* __restrict__ ei, int E, int* __restrict__ count,
                          float* __restrict__ dbg) {
  int i = blockIdx.x * 256 + threadIdx.x;
  if (i == 0) dbg[1] = 1001.0f;
  if (i < E) atomicAdd(&count[ei[E + i]], 1);
}

// ---------- stage 2: exclusive scan ----------
__global__ __launch_bounds__(256) void roen_scan(const int* __restrict__ count, int N,
                                                 int* __restrict__ off, int* __restrict__ cursor,
                                                 float* __restrict__ dbg) {
  __shared__ int tsum[256];
  int tid = threadIdx.x;
  if (tid == 0) dbg[2] = 1002.0f;
  int chunk = (N + 255) / 256;
  int b = tid * chunk;
  int e = b + chunk; if (e > N) e = N; if (b > N) b = N;
  int s = 0;
  for (int i = b; i < e; ++i) s += count[i];
  tsum[tid] = s;
  __syncthreads();
  for (int d = 1; d < 256; d <<= 1) {
    int t = (tid >= d) ? tsum[tid - d] : 0;
    __syncthreads();
    tsum[tid] += t;
    __syncthreads();
  }
  int run = tsum[tid] - s;
  for (int i = b; i < e; ++i) {
    off[i] = run; cursor[i] = run;
    run += count[i];
  }
  if (tid == 255) off[N] = run;
}

// ---------- stage 3: inverse permutation + src in sorted order ----------
__global__ void roen_scatter(const int* __restrict__ ei, int E, int* __restrict__ cursor,
                             int* __restrict__ inv, int* __restrict__ srcS,
                             float* __restrict__ dbg) {
  int i = blockIdx.x * 256 + threadIdx.x;
  if (i == 0) dbg[3] = 1003.0f;
  if (i < E) {
    int s = ei[i];
    int d = ei[E + i];
    int p = atomicAdd(&cursor[d], 1);
    inv[i] = p;
    srcS[p] = s;
  }
}

// ---------- stage 4: weights f32 -> bf16 transposed: Wt[w][n*128+k] = W[k][n] ----------
__global__ void roen_prep_w(const float* __restrict__ W0, const float* __restrict__ W1,
                            const float* __restrict__ W2, const float* __restrict__ W3,
                            const float* __restrict__ W4, u16* __restrict__ Wt,
                            float* __restrict__ dbg) {
  int w = blockIdx.x;
  if (w == 0 && threadIdx.x == 0) dbg[4] = 1004.0f;
  const float* W = (w == 0) ? W0 : (w == 1) ? W1 : (w == 2) ? W2 : (w == 3) ? W3 : W4;
  for (int idx = threadIdx.x; idx < 16384; idx += 256) {
    int n = idx >> 7, k = idx & 127;
    Wt[w * 16384 + idx] = f2bf(W[k * 128 + n]);
  }
}

// ---------- stage 5: fused q/k/v GEMM. B fragments from global (L2-hot) ----------
__global__ __launch_bounds__(256) void roen_gemm_qkv(const float* __restrict__ x,
                                                     const u16* __restrict__ Wt,
                                                     u16* __restrict__ qb, u16* __restrict__ kb,
                                                     u16* __restrict__ vb, int M,
                                                     float* __restrict__ dbg) {
  __shared__ u16 As[64 * 128];
  const int tid = threadIdx.x;
  if (blockIdx.x == 0 && tid == 0) dbg[5] = 1005.0f;
  const long brow = (long)blockIdx.x * 64;

  {
    f32x4 tmp[8];
#pragma unroll
    for (int j = 0; j < 8; ++j) {
      int idx = j * 256 + tid;
      int row = idx >> 5;
      int c4 = (idx & 31) * 4;
      long grow = brow + row;
      f32x4 a = {0.f, 0.f, 0.f, 0.f};
      if (grow < M) a = *(const f32x4*)(x + grow * 128 + c4);
      tmp[j] = a;
    }
#pragma unroll
    for (int j = 0; j < 8; ++j) {
      int idx = j * 256 + tid;
      int row = idx >> 5;
      int c4 = (idx & 31) * 4;
      u32 lo = ((u32)f2bf(tmp[j][1]) << 16) | (u32)f2bf(tmp[j][0]);
      u32 hi = ((u32)f2bf(tmp[j][3]) << 16) | (u32)f2bf(tmp[j][2]);
      int byte = (row * 256 + c4 * 2) ^ ((row & 7) << 4);
      u32x2 val; val[0] = lo; val[1] = hi;
      *(u32x2*)((char*)As + byte) = val;
    }
  }
  __syncthreads();

  const int wave = tid >> 6, lane = tid & 63;
  const int wc = wave * 32;
  const int lr = lane & 15, lg = lane >> 4;

  s16x8 af[4][4];  // [ks][mt]
#pragma unroll
  for (int ks = 0; ks < 4; ++ks) {
    int kb2 = (ks * 32 + lg * 8) * 2;
#pragma unroll
    for (int mt = 0; mt < 4; ++mt) {
      int row = mt * 16 + lr;
      int byte = (row * 256 + kb2) ^ ((row & 7) << 4);
      af[ks][mt] = *(const s16x8*)((const char*)As + byte);
    }
  }

  for (int w = 0; w < 3; ++w) {
    s16x8 bfr[4][2];
#pragma unroll
    for (int ks = 0; ks < 4; ++ks)
#pragma unroll
      for (int nt = 0; nt < 2; ++nt)
        bfr[ks][nt] = *(const s16x8*)(Wt + w * 16384 + (wc + nt * 16 + lr) * 128 + ks * 32 + lg * 8);

    f32x4 acc[4][2];
    for (int mt = 0; mt < 4; ++mt)
      for (int nt = 0; nt < 2; ++nt) acc[mt][nt] = {0.f, 0.f, 0.f, 0.f};

#pragma unroll
    for (int ks = 0; ks < 4; ++ks)
      for (int mt = 0; mt < 4; ++mt)
        for (int nt = 0; nt < 2; ++nt)
          acc[mt][nt] = __builtin_amdgcn_mfma_f32_16x16x32_bf16(af[ks][mt], bfr[ks][nt], acc[mt][nt], 0, 0, 0);

    u16* C = (w == 0) ? qb : (w == 1) ? kb : vb;
    for (int mt = 0; mt < 4; ++mt) {
      for (int nt = 0; nt < 2; ++nt) {
        int col = wc + nt * 16 + lr;
        for (int r = 0; r < 4; ++r) {
          long row = brow + mt * 16 + lg * 4 + r;
          if (row < M) C[row * 128 + col] = f2bf(acc[mt][nt][r]);
        }
      }
    }
  }
}

// ---------- stage 6: e-GEMM + FUSED score. Streaming read, scatter-write eS + wS ----------
__global__ __launch_bounds__(256) void roen_gemm_e(const float* __restrict__ ea,
                                                   const u16* __restrict__ WtE,
                                                   const int* __restrict__ inv,
                                                   const int* __restrict__ ei,
                                                   const u16* __restrict__ qb,
                                                   const u16* __restrict__ kb,
                                                   u16* __restrict__ eS,
                                                   float* __restrict__ wS, int E,
                                                   float* __restrict__ dbg) {
  __shared__ u16 As[128 * 128];
  __shared__ int invv[128];
  __shared__ int srcv[128];
  __shared__ int dstv[128];
  const int tid = threadIdx.x;
  if (blockIdx.x == 0 && tid == 0) dbg[6] = 1006.0f;
  const long brow = (long)blockIdx.x * 128;

  if (tid < 128) {
    long pos = brow + tid;
    invv[tid] = (pos < E) ? inv[pos] : -1;
    srcv[tid] = (pos < E) ? ei[pos] : 0;
  } else {
    long pos = brow + tid - 128;
    dstv[tid - 128] = (pos < E) ? ei[E + pos] : 0;
  }

  // batch-staged sequential loads
  {
    f32x4 tmp[16];
#pragma unroll
    for (int j = 0; j < 16; ++j) {
      int idx = j * 256 + tid;
      int row = idx >> 5;
      int c4 = (idx & 31) * 4;
      long grow = brow + row;
      f32x4 a = {0.f, 0.f, 0.f, 0.f};
      if (grow < E) a = *(const f32x4*)(ea + grow * 128 + c4);
      tmp[j] = a;
    }
#pragma unroll
    for (int j = 0; j < 16; ++j) {
      int idx = j * 256 + tid;
      int row = idx >> 5;
      int c4 = (idx & 31) * 4;
      u32 lo = ((u32)f2bf(tmp[j][1]) << 16) | (u32)f2bf(tmp[j][0]);
      u32 hi = ((u32)f2bf(tmp[j][3]) << 16) | (u32)f2bf(tmp[j][2]);
      int byte = (row * 256 + c4 * 2) ^ ((row & 7) << 4);
      u32x2 val; val[0] = lo; val[1] = hi;
      *(u32x2*)((char*)As + byte) = val;
    }
  }

  const int wave = tid >> 6, lane = tid & 63;
  const int wc = wave * 32;
  const int lr = lane & 15, lg = lane >> 4;

  s16x8 bfr[4][2];
#pragma unroll
  for (int ks = 0; ks < 4; ++ks)
#pragma unroll
    for (int nt = 0; nt < 2; ++nt)
      bfr[ks][nt] = *(const s16x8*)(WtE + (wc + nt * 16 + lr) * 128 + ks * 32 + lg * 8);

  __syncthreads();

  f32x4 acc[8][2];
  for (int mt = 0; mt < 8; ++mt)
    for (int nt = 0; nt < 2; ++nt) acc[mt][nt] = {0.f, 0.f, 0.f, 0.f};

  for (int ks = 0; ks < 4; ++ks) {
    int kb2 = (ks * 32 + lg * 8) * 2;
    s16x8 af[8];
    for (int mt = 0; mt < 8; ++mt) {
      int row = mt * 16 + lr;
      int byte = (row * 256 + kb2) ^ ((row & 7) << 4);
      af[mt] = *(const s16x8*)((const char*)As + byte);
    }
    for (int mt = 0; mt < 8; ++mt)
      for (int nt = 0; nt < 2; ++nt)
        acc[mt][nt] = __builtin_amdgcn_mfma_f32_16x16x32_bf16(af[mt], bfr[ks][nt], acc[mt][nt], 0, 0, 0);
  }

  // restage output tile in LDS linear [row][col]
  __syncthreads();
  for (int mt = 0; mt < 8; ++mt) {
    for (int nt = 0; nt < 2; ++nt) {
      int col = wc + nt * 16 + lr;
      for (int r = 0; r < 4; ++r) {
        int row = mt * 16 + lg * 4 + r;
        As[row * 128 + col] = f2bf(acc[mt][nt][r]);
      }
    }
  }
  __syncthreads();

  // per row: score (q[dst]·(k[src]+e) per head) + 256B eS scatter store
  const int d0 = lane * 2;
  const int hh = lane >> 3;
  for (int rr = 0; rr < 32; ++rr) {
    int row = wave * 32 + rr;
    int op = invv[row];
    if (op < 0) continue;
    u32 ev = *(const u32*)((const char*)As + row * 256 + lane * 4);
    int src = srcv[row], dst = dstv[row];
    u32 qv = *(const u32*)(qb + (long)dst * 128 + d0);
    u32 kv = *(const u32*)(kb + (long)src * 128 + d0);
    float e0 = bf2f((u16)(ev & 0xffffu)), e1 = bf2f((u16)(ev >> 16));
    float p = bf2f((u16)(qv & 0xffffu)) * (bf2f((u16)(kv & 0xffffu)) + e0) +
              bf2f((u16)(qv >> 16)) * (bf2f((u16)(kv >> 16)) + e1);
    p += __shfl_xor(p, 1);
    p += __shfl_xor(p, 2);
    p += __shfl_xor(p, 4);
    if ((lane & 7) == 0) wS[(long)op * 8 + hh] = __expf(fminf(p * 0.25f, 80.f));
    *(u32*)(eS + (long)op * 128 + d0) = ev;
  }
}

// ---------- stage 10: per-node weighted aggregation, 4-wide pipelined ----------
__global__ __launch_bounds__(256) void roen_node_agg(const int* __restrict__ off,
                                                     const int* __restrict__ srcS,
                                                     const u16* __restrict__ eS,
                                                     const u16* __restrict__ vb,
                                                     const float* __restrict__ wS,
                                                     float* __restrict__ outat, int N,
                                                     float* __restrict__ dbg) {
  int wave = threadIdx.x >> 6;
  int lane = threadIdx.x & 63;
  int node = blockIdx.x * 4 + wave;
  if (node == 0 && lane == 0) dbg[10] = 1010.0f;
  if (node >= N) return;
  int beg = off[node], end = off[node + 1];

  const int d0 = lane * 2;
  const int hh = lane >> 3;
  float acc0 = 0.f, acc1 = 0.f, dsum = 0.f;

  int pos = beg;
  for (; pos + 4 <= end; pos += 4) {
    int s0 = srcS[pos], s1 = srcS[pos + 1], s2 = srcS[pos + 2], s3 = srcS[pos + 3];
    float w0 = wS[(long)(pos + 0) * 8 + hh];
    float w1 = wS[(long)(pos + 1) * 8 + hh];
    float w2 = wS[(long)(pos + 2) * 8 + hh];
    float w3 = wS[(long)(pos + 3) * 8 + hh];
    u32 e0 = *(const u32*)(eS + (long)(pos + 0) * 128 + d0);
    u32 e1 = *(const u32*)(eS + (long)(pos + 1) * 128 + d0);
    u32 e2 = *(const u32*)(eS + (long)(pos + 2) * 128 + d0);
    u32 e3 = *(const u32*)(eS + (long)(pos + 3) * 128 + d0);
    u32 v0 = *(const u32*)(vb + (long)s0 * 128 + d0);
    u32 v1 = *(const u32*)(vb + (long)s1 * 128 + d0);
    u32 v2 = *(const u32*)(vb + (long)s2 * 128 + d0);
    u32 v3 = *(const u32*)(vb + (long)s3 * 128 + d0);
    acc0 += w0 * (bf2f((u16)(v0 & 0xffffu)) + bf2f((u16)(e0 & 0xffffu)));
    acc1 += w0 * (bf2f((u16)(v0 >> 16)) + bf2f((u16)(e0 >> 16)));
    acc0 += w1 * (bf2f((u16)(v1 & 0xffffu)) + bf2f((u16)(e1 & 0xffffu)));
    acc1 += w1 * (bf2f((u16)(v1 >> 16)) + bf2f((u16)(e1 >> 16)));
    acc0 += w2 * (bf2f((u16)(v2 & 0xffffu)) + bf2f((u16)(e2 & 0xffffu)));
    acc1 += w2 * (bf2f((u16)(v2 >> 16)) + bf2f((u16)(e2 >> 16)));
    acc0 += w3 * (bf2f((u16)(v3 & 0xffffu)) + bf2f((u16)(e3 & 0xffffu)));
    acc1 += w3 * (bf2f((u16)(v3 >> 16)) + bf2f((u16)(e3 >> 16)));
    dsum += w0; dsum += w1; dsum += w2; dsum += w3;
  }
  for (; pos < end; ++pos) {
    float w = wS[(long)pos * 8 + hh];
    u32 ev = *(const u32*)(eS + (long)pos * 128 + d0);
    int src = srcS[pos];
    u32 vv = *(const u32*)(vb + (long)src * 128 + d0);
    acc0 += w * (bf2f((u16)(vv & 0xffffu)) + bf2f((u16)(ev & 0xffffu)));
    acc1 += w * (bf2f((u16)(vv >> 16)) + bf2f((u16)(ev >> 16)));
    dsum += w;
  }
  float inv = 1.f / (dsum + 1e-16f);
  outat[(long)node * 128 + d0] = acc0 * inv;
  outat[(long)node * 128 + d0 + 1] = acc1 * inv;
}

// ---------- stage 11: out@Wout GEMM + FUSED h = .. + bout + x, block column sums ----------
__global__ __launch_bounds__(256) void roen_gemm_out(const float* __restrict__ A,
                                                     const u16* __restrict__ Wt,
                                                     const float* __restrict__ x,
                                                     const float* __restrict__ bo,
                                                     float* __restrict__ h,
                                                     float* __restrict__ psum,
                                                     float* __restrict__ psumsq, int M,
                                                     float* __restrict__ dbg) {
  __shared__ u16 As[64 * 128];
  const int tid = threadIdx.x;
  if (blockIdx.x == 0 && tid == 0) dbg[11] = 1011.0f;
  const long brow = (long)blockIdx.x * 64;

  {
    f32x4 tmp[8];
#pragma unroll
    for (int j = 0; j < 8; ++j) {
      int idx = j * 256 + tid;
      int row = idx >> 5;
      int c4 = (idx & 31) * 4;
      long grow = brow + row;
      f32x4 a = {0.f, 0.f, 0.f, 0.f};
      if (grow < M) a = *(const f32x4*)(A + grow * 128 + c4);
      tmp[j] = a;
    }
#pragma unroll
    for (int j = 0; j < 8; ++j) {
      int idx = j * 256 + tid;
      int row = idx >> 5;
      int c4 = (idx & 31) * 4;
      u32 lo = ((u32)f2bf(tmp[j][1]) << 16) | (u32)f2bf(tmp[j][0]);
      u32 hi = ((u32)f2bf(tmp[j][3]) << 16) | (u32)f2bf(tmp[j][2]);
      int byte = (row * 256 + c4 * 2) ^ ((row & 7) << 4);
      u32x2 val; val[0] = lo; val[1] = hi;
      *(u32x2*)((char*)As + byte) = val;
    }
  }

  const int wave = tid >> 6, lane = tid & 63;
  const int wc = wave * 32;
  const int lr = lane & 15, lg = lane >> 4;

  s16x8 bfr[4][2];
#pragma unroll
  for (int ks = 0; ks < 4; ++ks)
#pragma unroll
    for (int nt = 0; nt < 2; ++nt)
      bfr[ks][nt] = *(const s16x8*)(Wt + (wc + nt * 16 + lr) * 128 + ks * 32 + lg * 8);

  __syncthreads();

  f32x4 acc[4][2];
  for (int mt = 0; mt < 4; ++mt)
    for (int nt = 0; nt < 2; ++nt) acc[mt][nt] = {0.f, 0.f, 0.f, 0.f};

  for (int ks = 0; ks < 4; ++ks) {
    int kb2 = (ks * 32 + lg * 8) * 2;
    s16x8 af[4];
    for (int mt = 0; mt < 4; ++mt) {
      int row = mt * 16 + lr;
      int byte = (row * 256 + kb2) ^ ((row & 7) << 4);
      af[mt] = *(const s16x8*)((const char*)As + byte);
    }
    for (int mt = 0; mt < 4; ++mt)
      for (int nt = 0; nt < 2; ++nt)
        acc[mt][nt] = __builtin_amdgcn_mfma_f32_16x16x32_bf16(af[mt], bfr[ks][nt], acc[mt][nt], 0, 0, 0);
  }

  // epilogue: h = acc + bout + x; per-column partial sums over this block's 64 rows
  float b0 = bo[wc + lr];        // nt=0 column bias
  float b1 = bo[wc + 16 + lr];   // nt=1
  float cs[2] = {0.f, 0.f}, cs2[2] = {0.f, 0.f};
  for (int mt = 0; mt < 4; ++mt) {
    for (int nt = 0; nt < 2; ++nt) {
      int col = wc + nt * 16 + lr;
      float bb = (nt == 0) ? b0 : b1;
      for (int r = 0; r < 4; ++r) {
        long row = brow + mt * 16 + lg * 4 + r;
        if (row < M) {
          long idx = row * 128 + col;
          float val = acc[mt][nt][r] + bb + x[idx];
          h[idx] = val;
          cs[nt] += val;
          cs2[nt] += val * val;
        }
      }
    }
  }
#pragma unroll
  for (int nt = 0; nt < 2; ++nt) {
    cs[nt] += __shfl_xor(cs[nt], 16);
    cs[nt] += __shfl_xor(cs[nt], 32);
    cs2[nt] += __shfl_xor(cs2[nt], 16);
    cs2[nt] += __shfl_xor(cs2[nt], 32);
  }
  if (lg == 0) {
    int col0 = wc + lr;
    psum[(long)blockIdx.x * 128 + col0] = cs[0];
    psumsq[(long)blockIdx.x * 128 + col0] = cs2[0];
    psum[(long)blockIdx.x * 128 + col0 + 16] = cs[1];
    psumsq[(long)blockIdx.x * 128 + col0 + 16] = cs2[1];
  }
}

// ---------- stage 13: GraphNorm coefficients ----------
__global__ void roen_stats(const float* __restrict__ psum, const float* __restrict__ psumsq,
                           const float* __restrict__ gnw, const float* __restrict__ gnb,
                           const float* __restrict__ gnms, float* __restrict__ Ac,
                           float* __restrict__ Bc, int nb, int N, float* __restrict__ dbg) {
  int d = threadIdx.x;
  if (d == 0) dbg[13] = 1013.0f;
  float s = 0.f, s2 = 0.f;
  for (int i = 0; i < nb; ++i) {
    s += psum[(long)i * 128 + d];
    s2 += psumsq[(long)i * 128 + d];
  }
  float mean = s / (float)N;
  float mm = mean * gnms[d];
  float var = s2 / (float)N - 2.f * mm * mean + mm * mm;
  float scale = gnw[d] * rsqrtf(var + 1e-5f);
  Ac[d] = scale;
  Bc[d] = gnb[d] - mm * scale;
}

// ---------- final: normalize + exact GELU -> f32 out ----------
__global__ __launch_bounds__(256) void roen_final(const float* __restrict__ h,
                                                  const float* __restrict__ Ac,
                                                  const float* __restrict__ Bc,
                                                  float* __restrict__ out, long total) {
  long i = (long)blockIdx.x * 256 + threadIdx.x;
  if (i >= total) return;
  int d = (int)(i & 127);
  float v = h[i] * Ac[d] + Bc[d];
  out[i] = 0.5f * v * (1.f + erff(v * 0.70710678f));
}

extern "C" void kernel_launch(void* const* d_in, const int* in_sizes, int n_in,
                              void* d_out, int out_size, void* d_ws, size_t ws_size,
                              hipStream_t stream) {
  const float* x   = (const float*)d_in[0];
  const int*   ei  = (const int*)d_in[1];
  const float* ea  = (const float*)d_in[2];
  const float* WQ  = (const float*)d_in[3];
  const float* WK  = (const float*)d_in[4];
  const float* WV  = (const float*)d_in[5];
  const float* WE  = (const float*)d_in[6];
  const float* Wo  = (const float*)d_in[7];
  const float* bo  = (const float*)d_in[8];
  const float* gnw = (const float*)d_in[9];
  const float* gnb = (const float*)d_in[10];
  const float* gnms= (const float*)d_in[11];
  float* out = (float*)d_out;
  float* dbg = (float*)d_out;

  const int N = in_sizes[0] / 128;   // 20000
  const int E = in_sizes[1] / 2;     // 640000
  const int gN = (N + 63) / 64;      // out-GEMM blocks (also psum blocks)

  char* base = (char*)d_ws;
  size_t cur = 0;
  auto alloc = [&](size_t bytes) -> char* {
    char* r = base + cur;
    cur = (cur + bytes + 255) & ~(size_t)255;
    return r;
  };
  u16*   wt     = (u16*)alloc(5 * 16384 * sizeof(u16));
  u16*   qb     = (u16*)alloc((size_t)N * 128 * sizeof(u16));
  u16*   kb     = (u16*)alloc((size_t)N * 128 * sizeof(u16));
  u16*   vb     = (u16*)alloc((size_t)N * 128 * sizeof(u16));
  float* wS     = (float*)alloc((size_t)E * 8 * sizeof(float));
  int*   count  = (int*)alloc((size_t)N * sizeof(int));
  int*   offar  = (int*)alloc((size_t)(N + 1) * sizeof(int));
  int*   cursor = (int*)alloc((size_t)N * sizeof(int));
  int*   invar  = (int*)alloc((size_t)E * sizeof(int));
  int*   srcS   = (int*)alloc((size_t)E * sizeof(int));
  float* outat  = (float*)alloc((size_t)N * 128 * sizeof(float));
  float* psum   = (float*)alloc((size_t)gN * 128 * sizeof(float));
  float* psumsq = (float*)alloc((size_t)gN * 128 * sizeof(float));
  float* Ac     = (float*)alloc(128 * sizeof(float));
  float* Bc     = (float*)alloc(128 * sizeof(float));
  u16*   eS     = (u16*)alloc((size_t)E * 128 * sizeof(u16));  // 164 MB
  float* hbuf   = (float*)eS;  // alias: eS dead after node_agg; h written by gemm_out

  roen_zero<<<(N + 255) / 256, 256, 0, stream>>>(count, N, dbg);
  roen_hist<<<(E + 255) / 256, 256, 0, stream>>>(ei, E, count, dbg);
  roen_scan<<<1, 256, 0, stream>>>(count, N, offar, cursor, dbg);
  roen_scatter<<<(E + 255) / 256, 256, 0, stream>>>(ei, E, cursor, invar, srcS, dbg);
  roen_prep_w<<<5, 256, 0, stream>>>(WQ, WK, WV, WE, Wo, wt, dbg);

  roen_gemm_qkv<<<gN, 256, 0, stream>>>(x, wt, qb, kb, vb, N, dbg);
  roen_gemm_e<<<(E + 127) / 128, 256, 0, stream>>>(ea, wt + 3 * 16384, invar, ei, qb, kb, eS, wS, E, dbg);

  roen_node_agg<<<(N + 3) / 4, 256, 0, stream>>>(offar, srcS, eS, vb, wS, outat, N, dbg);

  roen_gemm_out<<<gN, 256, 0, stream>>>(outat, wt + 4 * 16384, x, bo, hbuf, psum, psumsq, N, dbg);
  roen_stats<<<1, 128, 0, stream>>>(psum, psumsq, gnw, gnb, gnms, Ac, Bc, gN, N, dbg);
  roen_final<<<(int)(((long)N * 128 + 255) / 256), 256, 0, stream>>>(hbuf, Ac, Bc, out, (long)N * 128);
}

// Round 10
// 457.555 us; speedup vs baseline: 1.3137x; 1.0986x over previous
//
#include <hip/hip_runtime.h>

using u16 = unsigned short;
using u32 = unsigned int;
typedef float f32x4 __attribute__((ext_vector_type(4)));
typedef short s16x8 __attribute__((ext_vector_type(8)));
typedef u32   u32x2 __attribute__((ext_vector_type(2)));
typedef u32   u32x4 __attribute__((ext_vector_type(4)));

__device__ __forceinline__ u16 f2bf(float f) {
  u32 u = __float_as_uint(f);
  u += 0x7fffu + ((u >> 16) & 1u);
  return (u16)(u >> 16);
}
__device__ __forceinline__ float bf2f(u16 h) {
  return __uint_as_float(((u32)h) << 16);
}

__global__ void ROEN_Final_33526514713351_kernel() {}

// Sentinel ladder: stage s writes 1000+s to d_out[s]; roen_final overwrites all.
// Fragment layout for eS2/vb2: row r, u32 j in [0,64): lo16 = dim 32*(j>>4)+(j&15),
// hi16 = that dim + 16. (Matches MFMA C/D cols nt=0/1 packed per wave.)

// ---------- stage 0 ----------
__global__ void roen_zero(int* __restrict__ count, int N, float* __restrict__ dbg) {
  int i = blockIdx.x * 256 + threadIdx.x;
  if (i == 0) dbg[0] = 1000.0f;
  if (i < N) count[i] = 0;
}

// ---------- stage 1 ----------
__global__ void roen_hist(const int* __restrict__ ei, int E, int* __restrict__ count,
                          float* __restrict__ dbg) {
  int i = blockIdx.x * 256 + threadIdx.x;
  if (i == 0) dbg[1] = 1001.0f;
  if (i < E) atomicAdd(&count[ei[E + i]], 1);
}

// ---------- stage 2: exclusive scan ----------
__global__ __launch_bounds__(256) void roen_scan(const int* __restrict__ count, int N,
                                                 int* __restrict__ off, int* __restrict__ cursor,
                                                 float* __restrict__ dbg) {
  __shared__ int tsum[256];
  int tid = threadIdx.x;
  if (tid == 0) dbg[2] = 1002.0f;
  int chunk = (N + 255) / 256;
  int b = tid * chunk;
  int e = b + chunk; if (e > N) e = N; if (b > N) b = N;
  int s = 0;
  for (int i = b; i < e; ++i) s += count[i];
  tsum[tid] = s;
  __syncthreads();
  for (int d = 1; d < 256; d <<= 1) {
    int t = (tid >= d) ? tsum[tid - d] : 0;
    __syncthreads();
    tsum[tid] += t;
    __syncthreads();
  }
  int run = tsum[tid] - s;
  for (int i = b; i < e; ++i) {
    off[i] = run; cursor[i] = run;
    run += count[i];
  }
  if (tid == 255) off[N] = run;
}

// ---------- stage 3: inverse permutation + src/dst in sorted order ----------
__global__ void roen_scatter(const int* __restrict__ ei, int E, int* __restrict__ cursor,
                             int* __restrict__ inv, int* __restrict__ srcS,
                             int* __restrict__ dstS, float* __restrict__ dbg) {
  int i = blockIdx.x * 256 + threadIdx.x;
  if (i == 0) dbg[3] = 1003.0f;
  if (i < E) {
    int s = ei[i];
    int d = ei[E + i];
    int p = atomicAdd(&cursor[d], 1);
    inv[i] = p;
    srcS[p] = s;
    dstS[p] = d;
  }
}

// ---------- stage 4: weights f32 -> bf16 transposed: Wt[w][n*128+k] = W[k][n] ----------
__global__ void roen_prep_w(const float* __restrict__ W0, const float* __restrict__ W1,
                            const float* __restrict__ W2, const float* __restrict__ W3,
                            const float* __restrict__ W4, u16* __restrict__ Wt,
                            float* __restrict__ dbg) {
  int w = blockIdx.x;
  if (w == 0 && threadIdx.x == 0) dbg[4] = 1004.0f;
  const float* W = (w == 0) ? W0 : (w == 1) ? W1 : (w == 2) ? W2 : (w == 3) ? W3 : W4;
  for (int idx = threadIdx.x; idx < 16384; idx += 256) {
    int n = idx >> 7, k = idx & 127;
    Wt[w * 16384 + idx] = f2bf(W[k * 128 + n]);
  }
}

// ---------- stage 5: fused q/k/v GEMM; q,k row layout, v fragment layout ----------
__global__ __launch_bounds__(256) void roen_gemm_qkv(const float* __restrict__ x,
                                                     const u16* __restrict__ Wt,
                                                     u16* __restrict__ qb, u16* __restrict__ kb,
                                                     u32* __restrict__ vb2, int M,
                                                     float* __restrict__ dbg) {
  __shared__ u16 As[64 * 128];
  const int tid = threadIdx.x;
  if (blockIdx.x == 0 && tid == 0) dbg[5] = 1005.0f;
  const long brow = (long)blockIdx.x * 64;

  {
    f32x4 tmp[8];
#pragma unroll
    for (int j = 0; j < 8; ++j) {
      int idx = j * 256 + tid;
      int row = idx >> 5;
      int c4 = (idx & 31) * 4;
      long grow = brow + row;
      f32x4 a = {0.f, 0.f, 0.f, 0.f};
      if (grow < M) a = *(const f32x4*)(x + grow * 128 + c4);
      tmp[j] = a;
    }
#pragma unroll
    for (int j = 0; j < 8; ++j) {
      int idx = j * 256 + tid;
      int row = idx >> 5;
      int c4 = (idx & 31) * 4;
      u32 lo = ((u32)f2bf(tmp[j][1]) << 16) | (u32)f2bf(tmp[j][0]);
      u32 hi = ((u32)f2bf(tmp[j][3]) << 16) | (u32)f2bf(tmp[j][2]);
      int byte = (row * 256 + c4 * 2) ^ ((row & 7) << 4);
      u32x2 val; val[0] = lo; val[1] = hi;
      *(u32x2*)((char*)As + byte) = val;
    }
  }
  __syncthreads();

  const int wave = tid >> 6, lane = tid & 63;
  const int wc = wave * 32;
  const int lr = lane & 15, lg = lane >> 4;

  s16x8 af[4][4];  // [ks][mt]
#pragma unroll
  for (int ks = 0; ks < 4; ++ks) {
    int kb2 = (ks * 32 + lg * 8) * 2;
#pragma unroll
    for (int mt = 0; mt < 4; ++mt) {
      int row = mt * 16 + lr;
      int byte = (row * 256 + kb2) ^ ((row & 7) << 4);
      af[ks][mt] = *(const s16x8*)((const char*)As + byte);
    }
  }

  for (int w = 0; w < 3; ++w) {
    s16x8 bfr[4][2];
#pragma unroll
    for (int ks = 0; ks < 4; ++ks)
#pragma unroll
      for (int nt = 0; nt < 2; ++nt)
        bfr[ks][nt] = *(const s16x8*)(Wt + w * 16384 + (wc + nt * 16 + lr) * 128 + ks * 32 + lg * 8);

    f32x4 acc[4][2];
    for (int mt = 0; mt < 4; ++mt)
      for (int nt = 0; nt < 2; ++nt) acc[mt][nt] = {0.f, 0.f, 0.f, 0.f};

#pragma unroll
    for (int ks = 0; ks < 4; ++ks)
      for (int mt = 0; mt < 4; ++mt)
        for (int nt = 0; nt < 2; ++nt)
          acc[mt][nt] = __builtin_amdgcn_mfma_f32_16x16x32_bf16(af[ks][mt], bfr[ks][nt], acc[mt][nt], 0, 0, 0);

    if (w == 2) {
      // v in fragment layout: one u32 per row per lane
      for (int mt = 0; mt < 4; ++mt) {
        for (int r = 0; r < 4; ++r) {
          long row = brow + mt * 16 + lg * 4 + r;
          if (row < M) {
            u32 val = (u32)f2bf(acc[mt][0][r]) | ((u32)f2bf(acc[mt][1][r]) << 16);
            vb2[row * 64 + wave * 16 + lr] = val;
          }
        }
      }
    } else {
      u16* C = (w == 0) ? qb : kb;
      for (int mt = 0; mt < 4; ++mt) {
        for (int nt = 0; nt < 2; ++nt) {
          int col = wc + nt * 16 + lr;
          for (int r = 0; r < 4; ++r) {
            long row = brow + mt * 16 + lg * 4 + r;
            if (row < M) C[row * 128 + col] = f2bf(acc[mt][nt][r]);
          }
        }
      }
    }
  }
}

// ---------- stage 6: e-GEMM. Streaming read, direct fragment-layout scatter store ----------
__global__ __launch_bounds__(256) void roen_gemm_e(const float* __restrict__ ea,
                                                   const u16* __restrict__ WtE,
                                                   const int* __restrict__ inv,
                                                   u32* __restrict__ eS2, int E,
                                                   float* __restrict__ dbg) {
  __shared__ u16 As[128 * 128];
  __shared__ int invv[128];
  const int tid = threadIdx.x;
  if (blockIdx.x == 0 && tid == 0) dbg[6] = 1006.0f;
  const long brow = (long)blockIdx.x * 128;

  if (tid < 128) {
    long pos = brow + tid;
    invv[tid] = (pos < E) ? inv[pos] : -1;
  }

  {
    f32x4 tmp[16];
#pragma unroll
    for (int j = 0; j < 16; ++j) {
      int idx = j * 256 + tid;
      int row = idx >> 5;
      int c4 = (idx & 31) * 4;
      long grow = brow + row;
      f32x4 a = {0.f, 0.f, 0.f, 0.f};
      if (grow < E) a = *(const f32x4*)(ea + grow * 128 + c4);
      tmp[j] = a;
    }
#pragma unroll
    for (int j = 0; j < 16; ++j) {
      int idx = j * 256 + tid;
      int row = idx >> 5;
      int c4 = (idx & 31) * 4;
      u32 lo = ((u32)f2bf(tmp[j][1]) << 16) | (u32)f2bf(tmp[j][0]);
      u32 hi = ((u32)f2bf(tmp[j][3]) << 16) | (u32)f2bf(tmp[j][2]);
      int byte = (row * 256 + c4 * 2) ^ ((row & 7) << 4);
      u32x2 val; val[0] = lo; val[1] = hi;
      *(u32x2*)((char*)As + byte) = val;
    }
  }

  const int wave = tid >> 6, lane = tid & 63;
  const int wc = wave * 32;
  const int lr = lane & 15, lg = lane >> 4;

  s16x8 bfr[4][2];
#pragma unroll
  for (int ks = 0; ks < 4; ++ks)
#pragma unroll
    for (int nt = 0; nt < 2; ++nt)
      bfr[ks][nt] = *(const s16x8*)(WtE + (wc + nt * 16 + lr) * 128 + ks * 32 + lg * 8);

  __syncthreads();

  f32x4 acc[8][2];
  for (int mt = 0; mt < 8; ++mt)
    for (int nt = 0; nt < 2; ++nt) acc[mt][nt] = {0.f, 0.f, 0.f, 0.f};

  for (int ks = 0; ks < 4; ++ks) {
    int kb2 = (ks * 32 + lg * 8) * 2;
    s16x8 af[8];
    for (int mt = 0; mt < 8; ++mt) {
      int row = mt * 16 + lr;
      int byte = (row * 256 + kb2) ^ ((row & 7) << 4);
      af[mt] = *(const s16x8*)((const char*)As + byte);
    }
    for (int mt = 0; mt < 8; ++mt)
      for (int nt = 0; nt < 2; ++nt)
        acc[mt][nt] = __builtin_amdgcn_mfma_f32_16x16x32_bf16(af[mt], bfr[ks][nt], acc[mt][nt], 0, 0, 0);
  }

  // direct fragment-layout scatter: 64B chunk per wave per row, fire-and-forget
  for (int mt = 0; mt < 8; ++mt) {
    for (int r = 0; r < 4; ++r) {
      int row = mt * 16 + lg * 4 + r;
      int op = invv[row];
      if (op >= 0) {
        u32 val = (u32)f2bf(acc[mt][0][r]) | ((u32)f2bf(acc[mt][1][r]) << 16);
        eS2[(long)op * 64 + wave * 16 + lr] = val;
      }
    }
  }
}

// ---------- stage 9: score -> w = exp(min(s/4,80)), sorted order, E x 8 parallel ----------
__global__ __launch_bounds__(256) void roen_score(const int* __restrict__ srcS,
                                                  const int* __restrict__ dstS,
                                                  const u16* __restrict__ qb,
                                                  const u16* __restrict__ kb,
                                                  const u32* __restrict__ eS2,
                                                  float* __restrict__ wS, int E,
                                                  float* __restrict__ dbg) {
  long gid = (long)blockIdx.x * 256 + threadIdx.x;
  if (gid == 0) dbg[9] = 1009.0f;
  long pos = gid >> 3;
  int h = (int)(gid & 7);
  if (pos >= E) return;
  int dst = dstS[pos], src = srcS[pos];
  const s16x8* qp = (const s16x8*)(qb + (long)dst * 128 + h * 16);
  const s16x8* kp = (const s16x8*)(kb + (long)src * 128 + h * 16);
  const u32x4* ep = (const u32x4*)(eS2 + (long)pos * 64 + (h >> 1) * 16);
  const int sh = (h & 1) * 16;
  float acc = 0.f;
#pragma unroll
  for (int c = 0; c < 2; ++c) {  // m = 8c .. 8c+7
    s16x8 qv = qp[c], kv = kp[c];
    u32x4 ea_ = ep[c * 2], eb_ = ep[c * 2 + 1];
#pragma unroll
    for (int j = 0; j < 4; ++j) {
      float e0 = bf2f((u16)(ea_[j] >> sh));
      float e1 = bf2f((u16)(eb_[j] >> sh));
      acc += bf2f((u16)qv[j]) * (bf2f((u16)kv[j]) + e0);
      acc += bf2f((u16)qv[j + 4]) * (bf2f((u16)kv[j + 4]) + e1);
    }
  }
  wS[pos * 8 + h] = __expf(fminf(acc * 0.25f, 80.f));
}

// ---------- stage 10: per-node aggregation, fragment layout, 4-wide pipelined ----------
__global__ __launch_bounds__(256) void roen_node_agg(const int* __restrict__ off,
                                                     const int* __restrict__ srcS,
                                                     const u32* __restrict__ eS2,
                                                     const u32* __restrict__ vb2,
                                                     const float* __restrict__ wS,
                                                     float* __restrict__ outat, int N,
                                                     float* __restrict__ dbg) {
  int wave = threadIdx.x >> 6;
  int lane = threadIdx.x & 63;
  int node = blockIdx.x * 4 + wave;
  if (node == 0 && lane == 0) dbg[10] = 1010.0f;
  if (node >= N) return;
  int beg = off[node], end = off[node + 1];

  const int dA = 32 * (lane >> 4) + (lane & 15);
  const int dB = dA + 16;
  const int hA = dA >> 4;   // = 2*(lane>>4)
  const int hB = hA + 1;
  float accA = 0.f, accB = 0.f, dsA = 0.f, dsB = 0.f;

  int pos = beg;
  for (; pos + 4 <= end; pos += 4) {
    int s0 = srcS[pos], s1 = srcS[pos + 1], s2 = srcS[pos + 2], s3 = srcS[pos + 3];
    float wa0 = wS[(long)(pos + 0) * 8 + hA], wb0 = wS[(long)(pos + 0) * 8 + hB];
    float wa1 = wS[(long)(pos + 1) * 8 + hA], wb1 = wS[(long)(pos + 1) * 8 + hB];
    float wa2 = wS[(long)(pos + 2) * 8 + hA], wb2 = wS[(long)(pos + 2) * 8 + hB];
    float wa3 = wS[(long)(pos + 3) * 8 + hA], wb3 = wS[(long)(pos + 3) * 8 + hB];
    u32 e0 = eS2[(long)(pos + 0) * 64 + lane];
    u32 e1 = eS2[(long)(pos + 1) * 64 + lane];
    u32 e2 = eS2[(long)(pos + 2) * 64 + lane];
    u32 e3 = eS2[(long)(pos + 3) * 64 + lane];
    u32 v0 = vb2[(long)s0 * 64 + lane];
    u32 v1 = vb2[(long)s1 * 64 + lane];
    u32 v2 = vb2[(long)s2 * 64 + lane];
    u32 v3 = vb2[(long)s3 * 64 + lane];
    accA += wa0 * (bf2f((u16)v0) + bf2f((u16)e0));
    accB += wb0 * (bf2f((u16)(v0 >> 16)) + bf2f((u16)(e0 >> 16)));
    accA += wa1 * (bf2f((u16)v1) + bf2f((u16)e1));
    accB += wb1 * (bf2f((u16)(v1 >> 16)) + bf2f((u16)(e1 >> 16)));
    accA += wa2 * (bf2f((u16)v2) + bf2f((u16)e2));
    accB += wb2 * (bf2f((u16)(v2 >> 16)) + bf2f((u16)(e2 >> 16)));
    accA += wa3 * (bf2f((u16)v3) + bf2f((u16)e3));
    accB += wb3 * (bf2f((u16)(v3 >> 16)) + bf2f((u16)(e3 >> 16)));
    dsA += wa0 + wa1 + wa2 + wa3;
    dsB += wb0 + wb1 + wb2 + wb3;
  }
  for (; pos < end; ++pos) {
    float wa = wS[(long)pos * 8 + hA], wb = wS[(long)pos * 8 + hB];
    u32 ev = eS2[(long)pos * 64 + lane];
    int src = srcS[pos];
    u32 vv = vb2[(long)src * 64 + lane];
    accA += wa * (bf2f((u16)vv) + bf2f((u16)ev));
    accB += wb * (bf2f((u16)(vv >> 16)) + bf2f((u16)(ev >> 16)));
    dsA += wa; dsB += wb;
  }
  outat[(long)node * 128 + dA] = accA / (dsA + 1e-16f);
  outat[(long)node * 128 + dB] = accB / (dsB + 1e-16f);
}

// ---------- stage 11: out@Wout GEMM + FUSED h = .. + bout + x, block column sums ----------
__global__ __launch_bounds__(256) void roen_gemm_out(const float* __restrict__ A,
                                                     const u16* __restrict__ Wt,
                                                     const float* __restrict__ x,
                                                     const float* __restrict__ bo,
                                                     float* __restrict__ h,
                                                     float* __restrict__ psum,
                                                     float* __restrict__ psumsq, int M,
                                                     float* __restrict__ dbg) {
  __shared__ u16 As[64 * 128];
  const int tid = threadIdx.x;
  if (blockIdx.x == 0 && tid == 0) dbg[11] = 1011.0f;
  const long brow = (long)blockIdx.x * 64;

  {
    f32x4 tmp[8];
#pragma unroll
    for (int j = 0; j < 8; ++j) {
      int idx = j * 256 + tid;
      int row = idx >> 5;
      int c4 = (idx & 31) * 4;
      long grow = brow + row;
      f32x4 a = {0.f, 0.f, 0.f, 0.f};
      if (grow < M) a = *(const f32x4*)(A + grow * 128 + c4);
      tmp[j] = a;
    }
#pragma unroll
    for (int j = 0; j < 8; ++j) {
      int idx = j * 256 + tid;
      int row = idx >> 5;
      int c4 = (idx & 31) * 4;
      u32 lo = ((u32)f2bf(tmp[j][1]) << 16) | (u32)f2bf(tmp[j][0]);
      u32 hi = ((u32)f2bf(tmp[j][3]) << 16) | (u32)f2bf(tmp[j][2]);
      int byte = (row * 256 + c4 * 2) ^ ((row & 7) << 4);
      u32x2 val; val[0] = lo; val[1] = hi;
      *(u32x2*)((char*)As + byte) = val;
    }
  }

  const int wave = tid >> 6, lane = tid & 63;
  const int wc = wave * 32;
  const int lr = lane & 15, lg = lane >> 4;

  s16x8 bfr[4][2];
#pragma unroll
  for (int ks = 0; ks < 4; ++ks)
#pragma unroll
    for (int nt = 0; nt < 2; ++nt)
      bfr[ks][nt] = *(const s16x8*)(Wt + (wc + nt * 16 + lr) * 128 + ks * 32 + lg * 8);

  __syncthreads();

  f32x4 acc[4][2];
  for (int mt = 0; mt < 4; ++mt)
    for (int nt = 0; nt < 2; ++nt) acc[mt][nt] = {0.f, 0.f, 0.f, 0.f};

  for (int ks = 0; ks < 4; ++ks) {
    int kb2 = (ks * 32 + lg * 8) * 2;
    s16x8 af[4];
    for (int mt = 0; mt < 4; ++mt) {
      int row = mt * 16 + lr;
      int byte = (row * 256 + kb2) ^ ((row & 7) << 4);
      af[mt] = *(const s16x8*)((const char*)As + byte);
    }
    for (int mt = 0; mt < 4; ++mt)
      for (int nt = 0; nt < 2; ++nt)
        acc[mt][nt] = __builtin_amdgcn_mfma_f32_16x16x32_bf16(af[mt], bfr[ks][nt], acc[mt][nt], 0, 0, 0);
  }

  float b0 = bo[wc + lr];
  float b1 = bo[wc + 16 + lr];
  float cs[2] = {0.f, 0.f}, cs2[2] = {0.f, 0.f};
  for (int mt = 0; mt < 4; ++mt) {
    for (int nt = 0; nt < 2; ++nt) {
      int col = wc + nt * 16 + lr;
      float bb = (nt == 0) ? b0 : b1;
      for (int r = 0; r < 4; ++r) {
        long row = brow + mt * 16 + lg * 4 + r;
        if (row < M) {
          long idx = row * 128 + col;
          float val = acc[mt][nt][r] + bb + x[idx];
          h[idx] = val;
          cs[nt] += val;
          cs2[nt] += val * val;
        }
      }
    }
  }
#pragma unroll
  for (int nt = 0; nt < 2; ++nt) {
    cs[nt] += __shfl_xor(cs[nt], 16);
    cs[nt] += __shfl_xor(cs[nt], 32);
    cs2[nt] += __shfl_xor(cs2[nt], 16);
    cs2[nt] += __shfl_xor(cs2[nt], 32);
  }
  if (lg == 0) {
    int col0 = wc + lr;
    psum[(long)blockIdx.x * 128 + col0] = cs[0];
    psumsq[(long)blockIdx.x * 128 + col0] = cs2[0];
    psum[(long)blockIdx.x * 128 + col0 + 16] = cs[1];
    psumsq[(long)blockIdx.x * 128 + col0 + 16] = cs2[1];
  }
}

// ---------- stage 13: GraphNorm coefficients ----------
__global__ void roen_stats(const float* __restrict__ psum, const float* __restrict__ psumsq,
                           const float* __restrict__ gnw, const float* __restrict__ gnb,
                           const float* __restrict__ gnms, float* __restrict__ Ac,
                           float* __restrict__ Bc, int nb, int N, float* __restrict__ dbg) {
  int d = threadIdx.x;
  if (d == 0) dbg[13] = 1013.0f;
  float s = 0.f, s2 = 0.f;
  for (int i = 0; i < nb; ++i) {
    s += psum[(long)i * 128 + d];
    s2 += psumsq[(long)i * 128 + d];
  }
  float mean = s / (float)N;
  float mm = mean * gnms[d];
  float var = s2 / (float)N - 2.f * mm * mean + mm * mm;
  float scale = gnw[d] * rsqrtf(var + 1e-5f);
  Ac[d] = scale;
  Bc[d] = gnb[d] - mm * scale;
}

// ---------- final: normalize + exact GELU -> f32 out ----------
__global__ __launch_bounds__(256) void roen_final(const float* __restrict__ h,
                                                  const float* __restrict__ Ac,
                                                  const float* __restrict__ Bc,
                                                  float* __restrict__ out, long total) {
  long i = (long)blockIdx.x * 256 + threadIdx.x;
  if (i >= total) return;
  int d = (int)(i & 127);
  float v = h[i] * Ac[d] + Bc[d];
  out[i] = 0.5f * v * (1.f + erff(v * 0.70710678f));
}

extern "C" void kernel_launch(void* const* d_in, const int* in_sizes, int n_in,
                              void* d_out, int out_size, void* d_ws, size_t ws_size,
                              hipStream_t stream) {
  const float* x   = (const float*)d_in[0];
  const int*   ei  = (const int*)d_in[1];
  const float* ea  = (const float*)d_in[2];
  const float* WQ  = (const float*)d_in[3];
  const float* WK  = (const float*)d_in[4];
  const float* WV  = (const float*)d_in[5];
  const float* WE  = (const float*)d_in[6];
  const float* Wo  = (const float*)d_in[7];
  const float* bo  = (const float*)d_in[8];
  const float* gnw = (const float*)d_in[9];
  const float* gnb = (const float*)d_in[10];
  const float* gnms= (const float*)d_in[11];
  float* out = (float*)d_out;
  float* dbg = (float*)d_out;

  const int N = in_sizes[0] / 128;   // 20000
  const int E = in_sizes[1] / 2;     // 640000
  const int gN = (N + 63) / 64;

  char* base = (char*)d_ws;
  size_t cur = 0;
  auto alloc = [&](size_t bytes) -> char* {
    char* r = base + cur;
    cur = (cur + bytes + 255) & ~(size_t)255;
    return r;
  };
  u16*   wt     = (u16*)alloc(5 * 16384 * sizeof(u16));
  u16*   qb     = (u16*)alloc((size_t)N * 128 * sizeof(u16));
  u16*   kb     = (u16*)alloc((size_t)N * 128 * sizeof(u16));
  u32*   vb2    = (u32*)alloc((size_t)N * 64 * sizeof(u32));
  float* wS     = (float*)alloc((size_t)E * 8 * sizeof(float));
  int*   count  = (int*)alloc((size_t)N * sizeof(int));
  int*   offar  = (int*)alloc((size_t)(N + 1) * sizeof(int));
  int*   cursor = (int*)alloc((size_t)N * sizeof(int));
  int*   invar  = (int*)alloc((size_t)E * sizeof(int));
  int*   srcS   = (int*)alloc((size_t)E * sizeof(int));
  int*   dstS   = (int*)alloc((size_t)E * sizeof(int));
  float* outat  = (float*)alloc((size_t)N * 128 * sizeof(float));
  float* psum   = (float*)alloc((size_t)gN * 128 * sizeof(float));
  float* psumsq = (float*)alloc((size_t)gN * 128 * sizeof(float));
  float* Ac     = (float*)alloc(128 * sizeof(float));
  float* Bc     = (float*)alloc(128 * sizeof(float));
  u32*   eS2    = (u32*)alloc((size_t)E * 64 * sizeof(u32));  // 164 MB
  float* hbuf   = (float*)eS2;  // alias: eS2 dead after node_agg

  roen_zero<<<(N + 255) / 256, 256, 0, stream>>>(count, N, dbg);
  roen_hist<<<(E + 255) / 256, 256, 0, stream>>>(ei, E, count, dbg);
  roen_scan<<<1, 256, 0, stream>>>(count, N, offar, cursor, dbg);
  roen_scatter<<<(E + 255) / 256, 256, 0, stream>>>(ei, E, cursor, invar, srcS, dstS, dbg);
  roen_prep_w<<<5, 256, 0, stream>>>(WQ, WK, WV, WE, Wo, wt, dbg);

  roen_gemm_qkv<<<gN, 256, 0, stream>>>(x, wt, qb, kb, vb2, N, dbg);
  roen_gemm_e<<<(E + 127) / 128, 256, 0, stream>>>(ea, wt + 3 * 16384, invar, eS2, E, dbg);

  roen_score<<<(int)(((long)E * 8 + 255) / 256), 256, 0, stream>>>(srcS, dstS, qb, kb, eS2, wS, E, dbg);
  roen_node_agg<<<(N + 3) / 4, 256, 0, stream>>>(offar, srcS, eS2, vb2, wS, outat, N, dbg);

  roen_gemm_out<<<gN, 256, 0, stream>>>(outat, wt + 4 * 16384, x, bo, hbuf, psum, psumsq, N, dbg);
  roen_stats<<<1, 128, 0, stream>>>(psum, psumsq, gnw, gnb, gnms, Ac, Bc, gN, N, dbg);
  roen_final<<<(int)(((long)N * 128 + 255) / 256), 256, 0, stream>>>(hbuf, Ac, Bc, out, (long)N * 128);
}

// Round 11
// 415.302 us; speedup vs baseline: 1.4473x; 1.1017x over previous
//
#include <hip/hip_runtime.h>

using u16 = unsigned short;
using u32 = unsigned int;
typedef float f32x4 __attribute__((ext_vector_type(4)));
typedef float f32x2 __attribute__((ext_vector_type(2)));
typedef short s16x8 __attribute__((ext_vector_type(8)));
typedef u32   u32x2 __attribute__((ext_vector_type(2)));
typedef u32   u32x4 __attribute__((ext_vector_type(4)));

__device__ __forceinline__ u16 f2bf(float f) {
  u32 u = __float_as_uint(f);
  u += 0x7fffu + ((u >> 16) & 1u);
  return (u16)(u >> 16);
}
__device__ __forceinline__ float bf2f(u16 h) {
  return __uint_as_float(((u32)h) << 16);
}

__global__ void ROEN_Final_33526514713351_kernel() {}

// Sentinel ladder: stage s writes 1000+s to d_out[s]; roen_final overwrites all.
// Fragment layout for eS2/vb2: row r, u32 j in [0,64): lo16 = dim 32*(j>>4)+(j&15),
// hi16 = that dim + 16. (Matches MFMA C/D cols nt=0/1 packed per wave.)

// ---------- stage 0 ----------
__global__ void roen_zero(int* __restrict__ count, int N, float* __restrict__ dbg) {
  int i = blockIdx.x * 256 + threadIdx.x;
  if (i == 0) dbg[0] = 1000.0f;
  if (i < N) count[i] = 0;
}

// ---------- stage 1: histogram + per-edge rank (atomic returns old -> rank) ----------
__global__ void roen_hist(const int* __restrict__ ei, int E, int* __restrict__ count,
                          int* __restrict__ rank, float* __restrict__ dbg) {
  int i = blockIdx.x * 256 + threadIdx.x;
  if (i == 0) dbg[1] = 1001.0f;
  if (i < E) rank[i] = atomicAdd(&count[ei[E + i]], 1);
}

// ---------- stage 2: exclusive scan, coalesced 1024-wide tiles + wave shfl-scan ----------
__global__ __launch_bounds__(1024) void roen_scan(const int* __restrict__ count, int N,
                                                  int* __restrict__ off,
                                                  float* __restrict__ dbg) {
  __shared__ int wsum[16];
  __shared__ int carrys;
  int tid = threadIdx.x, lane = tid & 63, wv = tid >> 6;
  if (tid == 0) { dbg[2] = 1002.0f; carrys = 0; }
  __syncthreads();
  for (int base = 0; base < N; base += 1024) {
    int i = base + tid;
    int v = (i < N) ? count[i] : 0;
    // wave inclusive scan
    int x = v;
#pragma unroll
    for (int s = 1; s < 64; s <<= 1) {
      int t = __shfl_up(x, s);
      if (lane >= s) x += t;
    }
    if (lane == 63) wsum[wv] = x;
    __syncthreads();
    if (wv == 0 && lane < 16) {
      int y = wsum[lane];
#pragma unroll
      for (int s = 1; s < 16; s <<= 1) {
        int t = __shfl_up(y, s);
        if (lane >= s) y += t;
      }
      wsum[lane] = y;
    }
    __syncthreads();
    int wbase = (wv == 0) ? 0 : wsum[wv - 1];
    int incl = x + wbase + carrys;
    if (i < N) off[i] = incl - v;
    __syncthreads();
    if (tid == 1023) carrys = incl;
    __syncthreads();
  }
  if (tid == 0) off[N] = carrys;
}

// ---------- stage 3: scatter WITHOUT atomics: pos = off[dst] + rank ----------
__global__ void roen_scatter(const int* __restrict__ ei, const int* __restrict__ off,
                             const int* __restrict__ rank, int E,
                             int* __restrict__ inv, int* __restrict__ srcS,
                             int* __restrict__ dstS, float* __restrict__ dbg) {
  int i = blockIdx.x * 256 + threadIdx.x;
  if (i == 0) dbg[3] = 1003.0f;
  if (i < E) {
    int d = ei[E + i];
    int p = off[d] + rank[i];
    inv[i] = p;
    srcS[p] = ei[i];
    dstS[p] = d;
  }
}

// ---------- stage 4: weights f32 -> bf16 transposed: Wt[w][n*128+k] = W[k][n] ----------
__global__ void roen_prep_w(const float* __restrict__ W0, const float* __restrict__ W1,
                            const float* __restrict__ W2, const float* __restrict__ W3,
                            const float* __restrict__ W4, u16* __restrict__ Wt,
                            float* __restrict__ dbg) {
  int w = blockIdx.x;
  if (w == 0 && threadIdx.x == 0) dbg[4] = 1004.0f;
  const float* W = (w == 0) ? W0 : (w == 1) ? W1 : (w == 2) ? W2 : (w == 3) ? W3 : W4;
  for (int idx = threadIdx.x; idx < 16384; idx += 256) {
    int n = idx >> 7, k = idx & 127;
    Wt[w * 16384 + idx] = f2bf(W[k * 128 + n]);
  }
}

// ---------- stage 5: fused q/k/v GEMM; q,k row layout, v fragment layout ----------
__global__ __launch_bounds__(256) void roen_gemm_qkv(const float* __restrict__ x,
                                                     const u16* __restrict__ Wt,
                                                     u16* __restrict__ qb, u16* __restrict__ kb,
                                                     u32* __restrict__ vb2, int M,
                                                     float* __restrict__ dbg) {
  __shared__ u16 As[64 * 128];
  const int tid = threadIdx.x;
  if (blockIdx.x == 0 && tid == 0) dbg[5] = 1005.0f;
  const long brow = (long)blockIdx.x * 64;

  {
    f32x4 tmp[8];
#pragma unroll
    for (int j = 0; j < 8; ++j) {
      int idx = j * 256 + tid;
      int row = idx >> 5;
      int c4 = (idx & 31) * 4;
      long grow = brow + row;
      f32x4 a = {0.f, 0.f, 0.f, 0.f};
      if (grow < M) a = *(const f32x4*)(x + grow * 128 + c4);
      tmp[j] = a;
    }
#pragma unroll
    for (int j = 0; j < 8; ++j) {
      int idx = j * 256 + tid;
      int row = idx >> 5;
      int c4 = (idx & 31) * 4;
      u32 lo = ((u32)f2bf(tmp[j][1]) << 16) | (u32)f2bf(tmp[j][0]);
      u32 hi = ((u32)f2bf(tmp[j][3]) << 16) | (u32)f2bf(tmp[j][2]);
      int byte = (row * 256 + c4 * 2) ^ ((row & 7) << 4);
      u32x2 val; val[0] = lo; val[1] = hi;
      *(u32x2*)((char*)As + byte) = val;
    }
  }
  __syncthreads();

  const int wave = tid >> 6, lane = tid & 63;
  const int wc = wave * 32;
  const int lr = lane & 15, lg = lane >> 4;

  s16x8 af[4][4];  // [ks][mt]
#pragma unroll
  for (int ks = 0; ks < 4; ++ks) {
    int kb2 = (ks * 32 + lg * 8) * 2;
#pragma unroll
    for (int mt = 0; mt < 4; ++mt) {
      int row = mt * 16 + lr;
      int byte = (row * 256 + kb2) ^ ((row & 7) << 4);
      af[ks][mt] = *(const s16x8*)((const char*)As + byte);
    }
  }

  for (int w = 0; w < 3; ++w) {
    s16x8 bfr[4][2];
#pragma unroll
    for (int ks = 0; ks < 4; ++ks)
#pragma unroll
      for (int nt = 0; nt < 2; ++nt)
        bfr[ks][nt] = *(const s16x8*)(Wt + w * 16384 + (wc + nt * 16 + lr) * 128 + ks * 32 + lg * 8);

    f32x4 acc[4][2];
    for (int mt = 0; mt < 4; ++mt)
      for (int nt = 0; nt < 2; ++nt) acc[mt][nt] = {0.f, 0.f, 0.f, 0.f};

#pragma unroll
    for (int ks = 0; ks < 4; ++ks)
      for (int mt = 0; mt < 4; ++mt)
        for (int nt = 0; nt < 2; ++nt)
          acc[mt][nt] = __builtin_amdgcn_mfma_f32_16x16x32_bf16(af[ks][mt], bfr[ks][nt], acc[mt][nt], 0, 0, 0);

    if (w == 2) {
      for (int mt = 0; mt < 4; ++mt) {
        for (int r = 0; r < 4; ++r) {
          long row = brow + mt * 16 + lg * 4 + r;
          if (row < M) {
            u32 val = (u32)f2bf(acc[mt][0][r]) | ((u32)f2bf(acc[mt][1][r]) << 16);
            vb2[row * 64 + wave * 16 + lr] = val;
          }
        }
      }
    } else {
      u16* C = (w == 0) ? qb : kb;
      for (int mt = 0; mt < 4; ++mt) {
        for (int nt = 0; nt < 2; ++nt) {
          int col = wc + nt * 16 + lr;
          for (int r = 0; r < 4; ++r) {
            long row = brow + mt * 16 + lg * 4 + r;
            if (row < M) C[row * 128 + col] = f2bf(acc[mt][nt][r]);
          }
        }
      }
    }
  }
}

// ---------- stage 6: e-GEMM, 64-row tile (higher occupancy), fragment scatter store ----------
__global__ __launch_bounds__(256) void roen_gemm_e(const float* __restrict__ ea,
                                                   const u16* __restrict__ WtE,
                                                   const int* __restrict__ inv,
                                                   u32* __restrict__ eS2, int E,
                                                   float* __restrict__ dbg) {
  __shared__ u16 As[64 * 128];
  __shared__ int invv[64];
  const int tid = threadIdx.x;
  if (blockIdx.x == 0 && tid == 0) dbg[6] = 1006.0f;
  const long brow = (long)blockIdx.x * 64;

  if (tid < 64) {
    long pos = brow + tid;
    invv[tid] = (pos < E) ? inv[pos] : -1;
  }

  {
    f32x4 tmp[8];
#pragma unroll
    for (int j = 0; j < 8; ++j) {
      int idx = j * 256 + tid;
      int row = idx >> 5;
      int c4 = (idx & 31) * 4;
      long grow = brow + row;
      f32x4 a = {0.f, 0.f, 0.f, 0.f};
      if (grow < E) a = *(const f32x4*)(ea + grow * 128 + c4);
      tmp[j] = a;
    }
#pragma unroll
    for (int j = 0; j < 8; ++j) {
      int idx = j * 256 + tid;
      int row = idx >> 5;
      int c4 = (idx & 31) * 4;
      u32 lo = ((u32)f2bf(tmp[j][1]) << 16) | (u32)f2bf(tmp[j][0]);
      u32 hi = ((u32)f2bf(tmp[j][3]) << 16) | (u32)f2bf(tmp[j][2]);
      int byte = (row * 256 + c4 * 2) ^ ((row & 7) << 4);
      u32x2 val; val[0] = lo; val[1] = hi;
      *(u32x2*)((char*)As + byte) = val;
    }
  }
  __syncthreads();

  const int wave = tid >> 6, lane = tid & 63;
  const int wc = wave * 32;
  const int lr = lane & 15, lg = lane >> 4;

  s16x8 bfr[4][2];
#pragma unroll
  for (int ks = 0; ks < 4; ++ks)
#pragma unroll
    for (int nt = 0; nt < 2; ++nt)
      bfr[ks][nt] = *(const s16x8*)(WtE + (wc + nt * 16 + lr) * 128 + ks * 32 + lg * 8);

  f32x4 acc[4][2];
  for (int mt = 0; mt < 4; ++mt)
    for (int nt = 0; nt < 2; ++nt) acc[mt][nt] = {0.f, 0.f, 0.f, 0.f};

  for (int ks = 0; ks < 4; ++ks) {
    int kb2 = (ks * 32 + lg * 8) * 2;
    s16x8 af[4];
    for (int mt = 0; mt < 4; ++mt) {
      int row = mt * 16 + lr;
      int byte = (row * 256 + kb2) ^ ((row & 7) << 4);
      af[mt] = *(const s16x8*)((const char*)As + byte);
    }
    for (int mt = 0; mt < 4; ++mt)
      for (int nt = 0; nt < 2; ++nt)
        acc[mt][nt] = __builtin_amdgcn_mfma_f32_16x16x32_bf16(af[mt], bfr[ks][nt], acc[mt][nt], 0, 0, 0);
  }

  // direct fragment-layout scatter: 64B chunk per wave per row, fire-and-forget
  for (int mt = 0; mt < 4; ++mt) {
    for (int r = 0; r < 4; ++r) {
      int row = mt * 16 + lg * 4 + r;
      int op = invv[row];
      if (op >= 0) {
        u32 val = (u32)f2bf(acc[mt][0][r]) | ((u32)f2bf(acc[mt][1][r]) << 16);
        eS2[(long)op * 64 + wave * 16 + lr] = val;
      }
    }
  }
}

// ---------- stage 9: score -> w = exp(min(s/4,80)), sorted order, E x 8 parallel ----------
__global__ __launch_bounds__(256) void roen_score(const int* __restrict__ srcS,
                                                  const int* __restrict__ dstS,
                                                  const u16* __restrict__ qb,
                                                  const u16* __restrict__ kb,
                                                  const u32* __restrict__ eS2,
                                                  float* __restrict__ wS, int E,
                                                  float* __restrict__ dbg) {
  long gid = (long)blockIdx.x * 256 + threadIdx.x;
  if (gid == 0) dbg[9] = 1009.0f;
  long pos = gid >> 3;
  int h = (int)(gid & 7);
  if (pos >= E) return;
  int dst = dstS[pos], src = srcS[pos];
  const s16x8* qp = (const s16x8*)(qb + (long)dst * 128 + h * 16);
  const s16x8* kp = (const s16x8*)(kb + (long)src * 128 + h * 16);
  const u32x4* ep = (const u32x4*)(eS2 + (long)pos * 64 + (h >> 1) * 16);
  const int sh = (h & 1) * 16;
  float acc = 0.f;
#pragma unroll
  for (int c = 0; c < 2; ++c) {
    s16x8 qv = qp[c], kv = kp[c];
    u32x4 ea_ = ep[c * 2], eb_ = ep[c * 2 + 1];
#pragma unroll
    for (int j = 0; j < 4; ++j) {
      float e0 = bf2f((u16)(ea_[j] >> sh));
      float e1 = bf2f((u16)(eb_[j] >> sh));
      acc += bf2f((u16)qv[j]) * (bf2f((u16)kv[j]) + e0);
      acc += bf2f((u16)qv[j + 4]) * (bf2f((u16)kv[j + 4]) + e1);
    }
  }
  wS[pos * 8 + h] = __expf(fminf(acc * 0.25f, 80.f));
}

// ---------- stage 10: per-node aggregation, fragment layout, 4-wide pipelined ----------
__global__ __launch_bounds__(256) void roen_node_agg(const int* __restrict__ off,
                                                     const int* __restrict__ srcS,
                                                     const u32* __restrict__ eS2,
                                                     const u32* __restrict__ vb2,
                                                     const float* __restrict__ wS,
                                                     float* __restrict__ outat, int N,
                                                     float* __restrict__ dbg) {
  int wave = threadIdx.x >> 6;
  int lane = threadIdx.x & 63;
  int node = blockIdx.x * 4 + wave;
  if (node == 0 && lane == 0) dbg[10] = 1010.0f;
  if (node >= N) return;
  int beg = off[node], end = off[node + 1];

  const int dA = 32 * (lane >> 4) + (lane & 15);
  const int dB = dA + 16;
  const int hA = dA >> 4;   // even
  float accA = 0.f, accB = 0.f, dsA = 0.f, dsB = 0.f;

  int pos = beg;
  for (; pos + 4 <= end; pos += 4) {
    int s0 = srcS[pos], s1 = srcS[pos + 1], s2 = srcS[pos + 2], s3 = srcS[pos + 3];
    f32x2 w0 = *(const f32x2*)(wS + (long)(pos + 0) * 8 + hA);
    f32x2 w1 = *(const f32x2*)(wS + (long)(pos + 1) * 8 + hA);
    f32x2 w2 = *(const f32x2*)(wS + (long)(pos + 2) * 8 + hA);
    f32x2 w3 = *(const f32x2*)(wS + (long)(pos + 3) * 8 + hA);
    u32 e0 = eS2[(long)(pos + 0) * 64 + lane];
    u32 e1 = eS2[(long)(pos + 1) * 64 + lane];
    u32 e2 = eS2[(long)(pos + 2) * 64 + lane];
    u32 e3 = eS2[(long)(pos + 3) * 64 + lane];
    u32 v0 = vb2[(long)s0 * 64 + lane];
    u32 v1 = vb2[(long)s1 * 64 + lane];
    u32 v2 = vb2[(long)s2 * 64 + lane];
    u32 v3 = vb2[(long)s3 * 64 + lane];
    accA += w0[0] * (bf2f((u16)v0) + bf2f((u16)e0));
    accB += w0[1] * (bf2f((u16)(v0 >> 16)) + bf2f((u16)(e0 >> 16)));
    accA += w1[0] * (bf2f((u16)v1) + bf2f((u16)e1));
    accB += w1[1] * (bf2f((u16)(v1 >> 16)) + bf2f((u16)(e1 >> 16)));
    accA += w2[0] * (bf2f((u16)v2) + bf2f((u16)e2));
    accB += w2[1] * (bf2f((u16)(v2 >> 16)) + bf2f((u16)(e2 >> 16)));
    accA += w3[0] * (bf2f((u16)v3) + bf2f((u16)e3));
    accB += w3[1] * (bf2f((u16)(v3 >> 16)) + bf2f((u16)(e3 >> 16)));
    dsA += w0[0] + w1[0] + w2[0] + w3[0];
    dsB += w0[1] + w1[1] + w2[1] + w3[1];
  }
  for (; pos < end; ++pos) {
    f32x2 w = *(const f32x2*)(wS + (long)pos * 8 + hA);
    u32 ev = eS2[(long)pos * 64 + lane];
    int src = srcS[pos];
    u32 vv = vb2[(long)src * 64 + lane];
    accA += w[0] * (bf2f((u16)vv) + bf2f((u16)ev));
    accB += w[1] * (bf2f((u16)(vv >> 16)) + bf2f((u16)(ev >> 16)));
    dsA += w[0]; dsB += w[1];
  }
  outat[(long)node * 128 + dA] = accA / (dsA + 1e-16f);
  outat[(long)node * 128 + dB] = accB / (dsB + 1e-16f);
}

// ---------- stage 11: out@Wout GEMM + FUSED h = .. + bout + x, block column sums ----------
__global__ __launch_bounds__(256) void roen_gemm_out(const float* __restrict__ A,
                                                     const u16* __restrict__ Wt,
                                                     const float* __restrict__ x,
                                                     const float* __restrict__ bo,
                                                     float* __restrict__ h,
                                                     float* __restrict__ psum,
                                                     float* __restrict__ psumsq, int M,
                                                     float* __restrict__ dbg) {
  __shared__ u16 As[64 * 128];
  const int tid = threadIdx.x;
  if (blockIdx.x == 0 && tid == 0) dbg[11] = 1011.0f;
  const long brow = (long)blockIdx.x * 64;

  {
    f32x4 tmp[8];
#pragma unroll
    for (int j = 0; j < 8; ++j) {
      int idx = j * 256 + tid;
      int row = idx >> 5;
      int c4 = (idx & 31) * 4;
      long grow = brow + row;
      f32x4 a = {0.f, 0.f, 0.f, 0.f};
      if (grow < M) a = *(const f32x4*)(A + grow * 128 + c4);
      tmp[j] = a;
    }
#pragma unroll
    for (int j = 0; j < 8; ++j) {
      int idx = j * 256 + tid;
      int row = idx >> 5;
      int c4 = (idx & 31) * 4;
      u32 lo = ((u32)f2bf(tmp[j][1]) << 16) | (u32)f2bf(tmp[j][0]);
      u32 hi = ((u32)f2bf(tmp[j][3]) << 16) | (u32)f2bf(tmp[j][2]);
      int byte = (row * 256 + c4 * 2) ^ ((row & 7) << 4);
      u32x2 val; val[0] = lo; val[1] = hi;
      *(u32x2*)((char*)As + byte) = val;
    }
  }

  const int wave = tid >> 6, lane = tid & 63;
  const int wc = wave * 32;
  const int lr = lane & 15, lg = lane >> 4;

  s16x8 bfr[4][2];
#pragma unroll
  for (int ks = 0; ks < 4; ++ks)
#pragma unroll
    for (int nt = 0; nt < 2; ++nt)
      bfr[ks][nt] = *(const s16x8*)(Wt + (wc + nt * 16 + lr) * 128 + ks * 32 + lg * 8);

  __syncthreads();

  f32x4 acc[4][2];
  for (int mt = 0; mt < 4; ++mt)
    for (int nt = 0; nt < 2; ++nt) acc[mt][nt] = {0.f, 0.f, 0.f, 0.f};

  for (int ks = 0; ks < 4; ++ks) {
    int kb2 = (ks * 32 + lg * 8) * 2;
    s16x8 af[4];
    for (int mt = 0; mt < 4; ++mt) {
      int row = mt * 16 + lr;
      int byte = (row * 256 + kb2) ^ ((row & 7) << 4);
      af[mt] = *(const s16x8*)((const char*)As + byte);
    }
    for (int mt = 0; mt < 4; ++mt)
      for (int nt = 0; nt < 2; ++nt)
        acc[mt][nt] = __builtin_amdgcn_mfma_f32_16x16x32_bf16(af[mt], bfr[ks][nt], acc[mt][nt], 0, 0, 0);
  }

  float b0 = bo[wc + lr];
  float b1 = bo[wc + 16 + lr];
  float cs[2] = {0.f, 0.f}, cs2[2] = {0.f, 0.f};
  for (int mt = 0; mt < 4; ++mt) {
    for (int nt = 0; nt < 2; ++nt) {
      int col = wc + nt * 16 + lr;
      float bb = (nt == 0) ? b0 : b1;
      for (int r = 0; r < 4; ++r) {
        long row = brow + mt * 16 + lg * 4 + r;
        if (row < M) {
          long idx = row * 128 + col;
          float val = acc[mt][nt][r] + bb + x[idx];
          h[idx] = val;
          cs[nt] += val;
          cs2[nt] += val * val;
        }
      }
    }
  }
#pragma unroll
  for (int nt = 0; nt < 2; ++nt) {
    cs[nt] += __shfl_xor(cs[nt], 16);
    cs[nt] += __shfl_xor(cs[nt], 32);
    cs2[nt] += __shfl_xor(cs2[nt], 16);
    cs2[nt] += __shfl_xor(cs2[nt], 32);
  }
  if (lg == 0) {
    int col0 = wc + lr;
    psum[(long)blockIdx.x * 128 + col0] = cs[0];
    psumsq[(long)blockIdx.x * 128 + col0] = cs2[0];
    psum[(long)blockIdx.x * 128 + col0 + 16] = cs[1];
    psumsq[(long)blockIdx.x * 128 + col0 + 16] = cs2[1];
  }
}

// ---------- stage 13: GraphNorm coefficients ----------
__global__ void roen_stats(const float* __restrict__ psum, const float* __restrict__ psumsq,
                           const float* __restrict__ gnw, const float* __restrict__ gnb,
                           const float* __restrict__ gnms, float* __restrict__ Ac,
                           float* __restrict__ Bc, int nb, int N, float* __restrict__ dbg) {
  int d = threadIdx.x;
  if (d == 0) dbg[13] = 1013.0f;
  float s = 0.f, s2 = 0.f;
  for (int i = 0; i < nb; ++i) {
    s += psum[(long)i * 128 + d];
    s2 += psumsq[(long)i * 128 + d];
  }
  float mean = s / (float)N;
  float mm = mean * gnms[d];
  float var = s2 / (float)N - 2.f * mm * mean + mm * mm;
  float scale = gnw[d] * rsqrtf(var + 1e-5f);
  Ac[d] = scale;
  Bc[d] = gnb[d] - mm * scale;
}

// ---------- final: normalize + exact GELU -> f32 out ----------
__global__ __launch_bounds__(256) void roen_final(const float* __restrict__ h,
                                                  const float* __restrict__ Ac,
                                                  const float* __restrict__ Bc,
                                                  float* __restrict__ out, long total) {
  long i = (long)blockIdx.x * 256 + threadIdx.x;
  if (i >= total) return;
  int d = (int)(i & 127);
  float v = h[i] * Ac[d] + Bc[d];
  out[i] = 0.5f * v * (1.f + erff(v * 0.70710678f));
}

extern "C" void kernel_launch(void* const* d_in, const int* in_sizes, int n_in,
                              void* d_out, int out_size, void* d_ws, size_t ws_size,
                              hipStream_t stream) {
  const float* x   = (const float*)d_in[0];
  const int*   ei  = (const int*)d_in[1];
  const float* ea  = (const float*)d_in[2];
  const float* WQ  = (const float*)d_in[3];
  const float* WK  = (const float*)d_in[4];
  const float* WV  = (const float*)d_in[5];
  const float* WE  = (const float*)d_in[6];
  const float* Wo  = (const float*)d_in[7];
  const float* bo  = (const float*)d_in[8];
  const float* gnw = (const float*)d_in[9];
  const float* gnb = (const float*)d_in[10];
  const float* gnms= (const float*)d_in[11];
  float* out = (float*)d_out;
  float* dbg = (float*)d_out;

  const int N = in_sizes[0] / 128;   // 20000
  const int E = in_sizes[1] / 2;     // 640000
  const int gN = (N + 63) / 64;

  char* base = (char*)d_ws;
  size_t cur = 0;
  auto alloc = [&](size_t bytes) -> char* {
    char* r = base + cur;
    cur = (cur + bytes + 255) & ~(size_t)255;
    return r;
  };
  u16*   wt     = (u16*)alloc(5 * 16384 * sizeof(u16));
  u16*   qb     = (u16*)alloc((size_t)N * 128 * sizeof(u16));
  u16*   kb     = (u16*)alloc((size_t)N * 128 * sizeof(u16));
  u32*   vb2    = (u32*)alloc((size_t)N * 64 * sizeof(u32));
  float* wS     = (float*)alloc((size_t)E * 8 * sizeof(float));
  int*   count  = (int*)alloc((size_t)N * sizeof(int));
  int*   offar  = (int*)alloc((size_t)(N + 1) * sizeof(int));
  int*   rank   = (int*)alloc((size_t)E * sizeof(int));
  int*   invar  = (int*)alloc((size_t)E * sizeof(int));
  int*   srcS   = (int*)alloc((size_t)E * sizeof(int));
  int*   dstS   = (int*)alloc((size_t)E * sizeof(int));
  float* outat  = (float*)alloc((size_t)N * 128 * sizeof(float));
  float* psum   = (float*)alloc((size_t)gN * 128 * sizeof(float));
  float* psumsq = (float*)alloc((size_t)gN * 128 * sizeof(float));
  float* Ac     = (float*)alloc(128 * sizeof(float));
  float* Bc     = (float*)alloc(128 * sizeof(float));
  u32*   eS2    = (u32*)alloc((size_t)E * 64 * sizeof(u32));  // 164 MB
  float* hbuf   = (float*)eS2;  // alias: eS2 dead after node_agg

  roen_zero<<<(N + 255) / 256, 256, 0, stream>>>(count, N, dbg);
  roen_hist<<<(E + 255) / 256, 256, 0, stream>>>(ei, E, count, rank, dbg);
  roen_scan<<<1, 1024, 0, stream>>>(count, N, offar, dbg);
  roen_scatter<<<(E + 255) / 256, 256, 0, stream>>>(ei, offar, rank, E, invar, srcS, dstS, dbg);
  roen_prep_w<<<5, 256, 0, stream>>>(WQ, WK, WV, WE, Wo, wt, dbg);

  roen_gemm_qkv<<<gN, 256, 0, stream>>>(x, wt, qb, kb, vb2, N, dbg);
  roen_gemm_e<<<(E + 63) / 64, 256, 0, stream>>>(ea, wt + 3 * 16384, invar, eS2, E, dbg);

  roen_score<<<(int)(((long)E * 8 + 255) / 256), 256, 0, stream>>>(srcS, dstS, qb, kb, eS2, wS, E, dbg);
  roen_node_agg<<<(N + 3) / 4, 256, 0, stream>>>(offar, srcS, eS2, vb2, wS, outat, N, dbg);

  roen_gemm_out<<<gN, 256, 0, stream>>>(outat, wt + 4 * 16384, x, bo, hbuf, psum, psumsq, N, dbg);
  roen_stats<<<1, 128, 0, stream>>>(psum, psumsq, gnw, gnb, gnms, Ac, Bc, gN, N, dbg);
  roen_final<<<(int)(((long)N * 128 + 255) / 256), 256, 0, stream>>>(hbuf, Ac, Bc, out, (long)N * 128);
}